// Round 4
// baseline (310.277 us; speedup 1.0000x reference)
//
#include <hip/hip_runtime.h>
#include <hip/hip_bf16.h>
#include <hip/hip_fp16.h>
#include <math.h>

#define N_NODES 20000
#define N_EDGES 320000
#define N_GRAPHS 64
#define OBS 64
#define EDGE_DIM 16
#define HEADS 4
#define HID 64
#define HC 256            // HEADS*HID
#define NEG_SLOPE 0.2f
#define EPSF 1e-16f
#define N_SCAN_BLOCKS ((N_NODES + 255) / 256)   // 79

// ---------------------------------------------------------------- utilities
__global__ __launch_bounds__(256) void zero_kernel(unsigned int* __restrict__ p, int n) {
    int i = blockIdx.x * 256 + threadIdx.x;
    if (i < n) p[i] = 0u;
}

// ---------------------------------------------------------------- CSR build
__global__ __launch_bounds__(256) void count_kernel(const int* __restrict__ ei, int* __restrict__ counts) {
    int e = blockIdx.x * 256 + threadIdx.x;
    if (e >= N_EDGES) return;
    atomicAdd(&counts[ei[N_EDGES + e]], 1);
}

__global__ __launch_bounds__(256) void scan_local_kernel(const int* __restrict__ counts,
                                                         int* __restrict__ row_start,
                                                         int* __restrict__ blk_tot) {
    int b = blockIdx.x, t = threadIdx.x;
    int i = b * 256 + t;
    int v = (i < N_NODES) ? counts[i] : 0;
    int lane = t & 63, w = t >> 6;
    int x = v;
    #pragma unroll
    for (int off = 1; off < 64; off <<= 1) {
        int y = __shfl_up(x, off, 64);
        if (lane >= off) x += y;
    }
    __shared__ int wsum[4];
    __shared__ int woff[4];
    if (lane == 63) wsum[w] = x;
    __syncthreads();
    if (t == 0) {
        int s = 0;
        #pragma unroll
        for (int k = 0; k < 4; ++k) { woff[k] = s; s += wsum[k]; }
        blk_tot[b] = s;
    }
    __syncthreads();
    if (i < N_NODES) row_start[i] = x - v + woff[w];
}

__global__ __launch_bounds__(128) void scan_offsets_kernel(const int* __restrict__ blk_tot,
                                                           int* __restrict__ blk_off) {
    __shared__ int sd[128];
    int t = threadIdx.x;
    int v = (t < N_SCAN_BLOCKS) ? blk_tot[t] : 0;
    sd[t] = v;
    __syncthreads();
    #pragma unroll
    for (int off = 1; off < 128; off <<= 1) {
        int add = (t >= off) ? sd[t - off] : 0;
        __syncthreads();
        sd[t] += add;
        __syncthreads();
    }
    if (t < N_SCAN_BLOCKS) blk_off[t] = sd[t] - v;
}

__global__ __launch_bounds__(256) void scan_add_kernel(int* __restrict__ row_start,
                                                       const int* __restrict__ blk_off,
                                                       int* __restrict__ cursor) {
    int b = blockIdx.x, t = threadIdx.x;
    int i = b * 256 + t;
    if (i >= N_NODES) return;
    int r = row_start[i] + blk_off[b];
    row_start[i] = r;
    cursor[i] = r;
}

// fill: also materialize src in CSR order + edge->pos map
__global__ __launch_bounds__(256) void fill_kernel(const int* __restrict__ ei,
                                                   int* __restrict__ cursor,
                                                   int* __restrict__ src_csr,
                                                   int* __restrict__ edge_pos) {
    int e = blockIdx.x * 256 + threadIdx.x;
    if (e >= N_EDGES) return;
    int s = ei[e];
    int d = ei[N_EDGES + e];
    int pos = atomicAdd(&cursor[d], 1);
    src_csr[pos] = s;
    edge_pos[e] = pos;
}

// ---------------------------------------------------------------- w_eff[h][d] = sum_c We[d, h*64+c] * att_edge[h,c]
__global__ void weff_kernel(const float* __restrict__ We, const float* __restrict__ att_edge,
                            float* __restrict__ w_eff) {
    int t = threadIdx.x;          // 64 threads
    int hh = t >> 4, d = t & 15;
    float acc = 0.f;
    #pragma unroll 8
    for (int c = 0; c < HID; ++c)
        acc += We[d * HC + hh * HID + c] * att_edge[hh * HID + c];
    w_eff[hh * 16 + d] = acc;
}

// ---------------------------------------------------------------- GEMM: C16[M,256] = fp16(X[M,K] @ W[K,256])
// fused epilogue: a_src[m,head] / a_dst[m,head] (BN == HID so each block = one head)
#define BM 64
#define BN 64
#define BK 16
__global__ __launch_bounds__(256) void gemm_kernel(const float* __restrict__ X,
                                                   const float* __restrict__ W,
                                                   __half* __restrict__ C16, int M, int K,
                                                   const float* __restrict__ att_src,
                                                   const float* __restrict__ att_dst,
                                                   float* __restrict__ a_src,
                                                   float* __restrict__ a_dst) {
    __shared__ float As[BK][68];   // padded
    __shared__ float Bs[BK][64];
    int t = threadIdx.x;
    int tx = t & 15, ty = t >> 4;
    int m0 = blockIdx.x * BM;
    int n0 = blockIdx.y * BN;
    float acc[4][4] = {};
    for (int k0 = 0; k0 < K; k0 += BK) {
        {
            int r = t >> 2, q = t & 3;
            int m = m0 + r;
            float4 v = make_float4(0.f, 0.f, 0.f, 0.f);
            if (m < M) v = *(const float4*)(X + (size_t)m * K + k0 + q * 4);
            As[q * 4 + 0][r] = v.x;
            As[q * 4 + 1][r] = v.y;
            As[q * 4 + 2][r] = v.z;
            As[q * 4 + 3][r] = v.w;
        }
        {
            int kr = t >> 4, n4 = (t & 15) * 4;
            float4 v = *(const float4*)(W + (size_t)(k0 + kr) * HC + n0 + n4);
            *(float4*)&Bs[kr][n4] = v;
        }
        __syncthreads();
        #pragma unroll
        for (int kk = 0; kk < BK; ++kk) {
            float4 a4 = *(const float4*)&As[kk][ty * 4];
            float4 b4 = *(const float4*)&Bs[kk][tx * 4];
            float av[4] = {a4.x, a4.y, a4.z, a4.w};
            float bv[4] = {b4.x, b4.y, b4.z, b4.w};
            #pragma unroll
            for (int i = 0; i < 4; ++i)
                #pragma unroll
                for (int j = 0; j < 4; ++j)
                    acc[i][j] += av[i] * bv[j];
        }
        __syncthreads();
    }
    #pragma unroll
    for (int i = 0; i < 4; ++i) {
        int m = m0 + ty * 4 + i;
        if (m < M) {
            __half2 p0 = __floats2half2_rn(acc[i][0], acc[i][1]);
            __half2 p1 = __floats2half2_rn(acc[i][2], acc[i][3]);
            __half* dst = C16 + (size_t)m * HC + n0 + tx * 4;
            *(__half2*)dst       = p0;
            *(__half2*)(dst + 2) = p1;
        }
    }
    // ---- fused attdot epilogue: this block covers head = n0/64
    {
        int head = n0 >> 6;
        float as[4], ad[4];
        #pragma unroll
        for (int j = 0; j < 4; ++j) {
            as[j] = att_src[head * HID + tx * 4 + j];
            ad[j] = att_dst[head * HID + tx * 4 + j];
        }
        #pragma unroll
        for (int i = 0; i < 4; ++i) {
            float ps = 0.f, pd = 0.f;
            #pragma unroll
            for (int j = 0; j < 4; ++j) {
                ps += acc[i][j] * as[j];
                pd += acc[i][j] * ad[j];
            }
            #pragma unroll
            for (int o = 8; o > 0; o >>= 1) {
                ps += __shfl_xor(ps, o, 64);
                pd += __shfl_xor(pd, o, 64);
            }
            int m = m0 + ty * 4 + i;
            if (tx == 0 && m < M) {
                a_src[(size_t)m * 4 + head] = ps;
                a_dst[(size_t)m * 4 + head] = pd;
            }
        }
    }
}

// ---------------------------------------------------------------- per-edge raw attention logits -> CSR order
__global__ __launch_bounds__(256) void alpha_kernel(const int* __restrict__ ei,
                                                    const float* __restrict__ edge_attr,
                                                    const float* __restrict__ w_eff,
                                                    const float* __restrict__ a_src,
                                                    const float* __restrict__ a_dst,
                                                    const int* __restrict__ edge_pos,
                                                    float4* __restrict__ alpha_csr) {
    __shared__ float wsh[64];
    int t = threadIdx.x;
    if (t < 64) wsh[t] = w_eff[t];
    __syncthreads();
    int e = blockIdx.x * 256 + t;
    if (e >= N_EDGES) return;
    int s = ei[e], d = ei[N_EDGES + e];
    const float* ea = edge_attr + (size_t)e * EDGE_DIM;
    float x[16];
    #pragma unroll
    for (int i = 0; i < 16; i += 4) {
        float4 v = *(const float4*)(ea + i);
        x[i] = v.x; x[i + 1] = v.y; x[i + 2] = v.z; x[i + 3] = v.w;
    }
    float4 as = *(const float4*)(a_src + (size_t)s * 4);
    float4 ad = *(const float4*)(a_dst + (size_t)d * 4);
    float asv[4] = {as.x, as.y, as.z, as.w};
    float adv[4] = {ad.x, ad.y, ad.z, ad.w};
    float al[4];
    #pragma unroll
    for (int hh = 0; hh < 4; ++hh) {
        float acc = 0.f;
        #pragma unroll
        for (int i = 0; i < 16; ++i) acc += x[i] * wsh[hh * 16 + i];
        float v = asv[hh] + adv[hh] + acc;
        al[hh] = v > 0.f ? v : NEG_SLOPE * v;   // leaky_relu
    }
    alpha_csr[edge_pos[e]] = make_float4(al[0], al[1], al[2], al[3]);
}

// ---------------------------------------------------------------- aggregate: wave per node, softmax + fp16 gather
// lane l handles channels (2l,2l+1) [heads 0/1] and (128+2l,128+2l+1) [heads 2/3]
__global__ __launch_bounds__(256) void aggregate_kernel(const int* __restrict__ src_csr,
                                                        const float4* __restrict__ alpha_csr,
                                                        const int* __restrict__ row_start,
                                                        const int* __restrict__ counts,
                                                        const __half* __restrict__ h16,
                                                        const float* __restrict__ bias,
                                                        float* __restrict__ out) {
    int wid = threadIdx.x >> 6, lane = threadIdx.x & 63;
    int n = blockIdx.x * 4 + wid;
    if (n >= N_NODES) return;
    int start = row_start[n];
    int deg = counts[n];
    const float4* ap = alpha_csr + start;
    const int* sp = src_csr + start;

    // pass A: per-head max over incoming edges (lane-parallel, sequential reads)
    float m0 = -INFINITY, m1 = -INFINITY, m2 = -INFINITY, m3 = -INFINITY;
    for (int i = lane; i < deg; i += 64) {
        float4 a = ap[i];
        m0 = fmaxf(m0, a.x); m1 = fmaxf(m1, a.y);
        m2 = fmaxf(m2, a.z); m3 = fmaxf(m3, a.w);
    }
    #pragma unroll
    for (int o = 32; o > 0; o >>= 1) {
        m0 = fmaxf(m0, __shfl_xor(m0, o, 64));
        m1 = fmaxf(m1, __shfl_xor(m1, o, 64));
        m2 = fmaxf(m2, __shfl_xor(m2, o, 64));
        m3 = fmaxf(m3, __shfl_xor(m3, o, 64));
    }
    bool lo = (lane < 32);
    float mA = lo ? m0 : m1;          // head for channels 2l
    float mB = lo ? m2 : m3;          // head for channels 128+2l

    // pass B: serial over edges; prefetch src one iteration ahead
    float aAx = 0.f, aAy = 0.f, aBx = 0.f, aBy = 0.f;
    float dA = 0.f, dB = 0.f;
    int s_next = (deg > 0) ? sp[0] : 0;
    #pragma unroll 2
    for (int i = 0; i < deg; ++i) {
        int s = s_next;
        if (i + 1 < deg) s_next = sp[i + 1];
        float4 a = ap[i];
        float eA = __expf((lo ? a.x : a.y) - mA);
        float eB = __expf((lo ? a.z : a.w) - mB);
        dA += eA; dB += eB;
        const __half2* hr = (const __half2*)(h16 + (size_t)s * HC);
        __half2 vA = hr[lane];        // channels 2l, 2l+1
        __half2 vB = hr[64 + lane];   // channels 128+2l, 128+2l+1
        float2 fA = __half22float2(vA);
        float2 fB = __half22float2(vB);
        aAx += eA * fA.x; aAy += eA * fA.y;
        aBx += eB * fB.x; aBy += eB * fB.y;
    }
    float2 b01 = *(const float2*)(bias + 2 * lane);
    float2 b23 = *(const float2*)(bias + 128 + 2 * lane);
    float invA = 1.f / (dA + EPSF);
    float invB = 1.f / (dB + EPSF);
    float2 r01 = make_float2(fmaxf(aAx * invA + b01.x, 0.f), fmaxf(aAy * invA + b01.y, 0.f));
    float2 r23 = make_float2(fmaxf(aBx * invB + b23.x, 0.f), fmaxf(aBy * invB + b23.y, 0.f));
    float* o = out + (size_t)n * HC;
    *(float2*)(o + 2 * lane)       = r01;
    *(float2*)(o + 128 + 2 * lane) = r23;
}

// ---------------------------------------------------------------- pooling (batch is sorted)
#define NPB 100
__global__ __launch_bounds__(256) void pool_kernel(const float* __restrict__ h,
                                                   const int* __restrict__ batch,
                                                   float* __restrict__ pooled,
                                                   int* __restrict__ gcounts) {
    int t = threadIdx.x;
    int n0 = blockIdx.x * NPB;
    int n1 = n0 + NPB;
    if (n1 > N_NODES) n1 = N_NODES;
    if (n0 >= N_NODES) return;
    int cur = batch[n0];
    float acc = 0.f;
    int cnt = 0;
    for (int n = n0; n < n1; ++n) {
        int g = batch[n];
        if (g != cur) {
            atomicAdd(&pooled[cur * HC + t], acc);
            if (t == 0) atomicAdd(&gcounts[cur], cnt);
            acc = 0.f; cnt = 0; cur = g;
        }
        acc += h[(size_t)n * HC + t];
        cnt++;
    }
    atomicAdd(&pooled[cur * HC + t], acc);
    if (t == 0) atomicAdd(&gcounts[cur], cnt);
}

__global__ __launch_bounds__(256) void finalize_kernel(const float* __restrict__ pooled,
                                                       const int* __restrict__ gcounts,
                                                       float* __restrict__ out) {
    int g = blockIdx.x, t = threadIdx.x;
    float c = (float)(gcounts[g] > 1 ? gcounts[g] : 1);
    out[g * HC + t] = tanhf(pooled[g * HC + t] / c);
}

// ---------------------------------------------------------------- launch
extern "C" void kernel_launch(void* const* d_in, const int* in_sizes, int n_in,
                              void* d_out, int out_size, void* d_ws, size_t ws_size,
                              hipStream_t stream) {
    const float* x         = (const float*)d_in[0];
    const int*   ei        = (const int*)d_in[1];
    const float* edge_attr = (const float*)d_in[2];
    const int*   batch     = (const int*)d_in[3];
    const float* Wl[3]  = {(const float*)d_in[4],  (const float*)d_in[10], (const float*)d_in[16]};
    const float* Wel[3] = {(const float*)d_in[5],  (const float*)d_in[11], (const float*)d_in[17]};
    const float* asl[3] = {(const float*)d_in[6],  (const float*)d_in[12], (const float*)d_in[18]};
    const float* adl[3] = {(const float*)d_in[7],  (const float*)d_in[13], (const float*)d_in[19]};
    const float* ael[3] = {(const float*)d_in[8],  (const float*)d_in[14], (const float*)d_in[20]};
    const float* bl[3]  = {(const float*)d_in[9],  (const float*)d_in[15], (const float*)d_in[21]};
    float* out = (float*)d_out;

    // workspace carve (256B aligned)
    char* p = (char*)d_ws;
    auto alloc = [&](size_t bytes) -> void* {
        void* r = (void*)p;
        p += (bytes + 255) & ~(size_t)255;
        return r;
    };
    __half* h16       = (__half*)alloc((size_t)N_NODES * HC * 2);
    float* hB         = (float*)alloc((size_t)N_NODES * HC * 4);
    float* a_src      = (float*)alloc((size_t)N_NODES * 4 * 4);
    float* a_dst      = (float*)alloc((size_t)N_NODES * 4 * 4);
    float4* alpha_csr = (float4*)alloc((size_t)N_EDGES * 16);
    int* counts       = (int*)alloc((size_t)N_NODES * 4);
    int* row_start    = (int*)alloc((size_t)N_NODES * 4);
    int* cursor       = (int*)alloc((size_t)N_NODES * 4);
    int* src_csr      = (int*)alloc((size_t)N_EDGES * 4);
    int* edge_pos     = (int*)alloc((size_t)N_EDGES * 4);
    float* w_eff      = (float*)alloc(64 * 4);
    float* pooled     = (float*)alloc((size_t)N_GRAPHS * HC * 4);
    int* gcounts      = (int*)alloc((size_t)N_GRAPHS * 4);
    int* blk_tot      = (int*)alloc((size_t)N_SCAN_BLOCKS * 4);
    int* blk_off      = (int*)alloc((size_t)N_SCAN_BLOCKS * 4);

    // zero scratch that accumulates
    zero_kernel<<<(N_NODES + 255) / 256, 256, 0, stream>>>((unsigned int*)counts, N_NODES);
    zero_kernel<<<(N_GRAPHS * HC + 255) / 256, 256, 0, stream>>>((unsigned int*)pooled, N_GRAPHS * HC);
    zero_kernel<<<1, 256, 0, stream>>>((unsigned int*)gcounts, N_GRAPHS);

    // CSR build over dst (parallel two-level scan)
    count_kernel<<<N_EDGES / 256, 256, 0, stream>>>(ei, counts);
    scan_local_kernel<<<N_SCAN_BLOCKS, 256, 0, stream>>>(counts, row_start, blk_tot);
    scan_offsets_kernel<<<1, 128, 0, stream>>>(blk_tot, blk_off);
    scan_add_kernel<<<N_SCAN_BLOCKS, 256, 0, stream>>>(row_start, blk_off, cursor);
    fill_kernel<<<N_EDGES / 256, 256, 0, stream>>>(ei, cursor, src_csr, edge_pos);

    const float* cur_in = x;
    int K = OBS;
    for (int l = 0; l < 3; ++l) {
        dim3 ggrid((N_NODES + BM - 1) / BM, HC / BN);
        gemm_kernel<<<ggrid, 256, 0, stream>>>(cur_in, Wl[l], h16, N_NODES, K,
                                               asl[l], adl[l], a_src, a_dst);
        weff_kernel<<<1, 64, 0, stream>>>(Wel[l], ael[l], w_eff);
        alpha_kernel<<<N_EDGES / 256, 256, 0, stream>>>(ei, edge_attr, w_eff, a_src, a_dst,
                                                        edge_pos, alpha_csr);
        aggregate_kernel<<<(N_NODES + 3) / 4, 256, 0, stream>>>(src_csr, alpha_csr, row_start,
                                                                counts, h16, bl[l], hB);
        cur_in = hB;
        K = HC;
    }

    // global mean pool + tanh
    pool_kernel<<<(N_NODES + NPB - 1) / NPB, 256, 0, stream>>>(hB, batch, pooled, gcounts);
    finalize_kernel<<<N_GRAPHS, 256, 0, stream>>>(pooled, gcounts, out);
}

// Round 5
// 280.981 us; speedup vs baseline: 1.1043x; 1.1043x over previous
//
#include <hip/hip_runtime.h>
#include <hip/hip_bf16.h>
#include <hip/hip_fp16.h>
#include <math.h>

#define N_NODES 20000
#define N_EDGES 320000
#define N_GRAPHS 64
#define OBS 64
#define EDGE_DIM 16
#define HEADS 4
#define HID 64
#define HC 256            // HEADS*HID
#define NEG_SLOPE 0.2f
#define EPSF 1e-16f
#define N_SCAN_BLOCKS ((N_NODES + 255) / 256)   // 79

typedef _Float16 f16x8 __attribute__((ext_vector_type(8)));
typedef float f32x4 __attribute__((ext_vector_type(4)));

// ---------------------------------------------------------------- utilities
__global__ __launch_bounds__(256) void zero_kernel(unsigned int* __restrict__ p, int n) {
    int i = blockIdx.x * 256 + threadIdx.x;
    if (i < n) p[i] = 0u;
}

// f32 -> f16 convert (n divisible by 4)
__global__ __launch_bounds__(256) void cvt_kernel(const float* __restrict__ in,
                                                  __half* __restrict__ out, int n) {
    int i = (blockIdx.x * 256 + threadIdx.x) * 4;
    if (i >= n) return;
    float4 v = *(const float4*)(in + i);
    *(__half2*)(out + i)     = __floats2half2_rn(v.x, v.y);
    *(__half2*)(out + i + 2) = __floats2half2_rn(v.z, v.w);
}

// Wt[n][k] = (f16) W[k][n]   (grid = K blocks, 256 threads)
__global__ __launch_bounds__(256) void wt_kernel(const float* __restrict__ W,
                                                 __half* __restrict__ Wt, int K) {
    int k = blockIdx.x;
    int n = threadIdx.x;
    Wt[(size_t)n * K + k] = __float2half(W[(size_t)k * HC + n]);
}

// ---------------------------------------------------------------- CSR build
__global__ __launch_bounds__(256) void count_kernel(const int* __restrict__ ei, int* __restrict__ counts) {
    int e = blockIdx.x * 256 + threadIdx.x;
    if (e >= N_EDGES) return;
    atomicAdd(&counts[ei[N_EDGES + e]], 1);
}

__global__ __launch_bounds__(256) void scan_local_kernel(const int* __restrict__ counts,
                                                         int* __restrict__ row_start,
                                                         int* __restrict__ blk_tot) {
    int b = blockIdx.x, t = threadIdx.x;
    int i = b * 256 + t;
    int v = (i < N_NODES) ? counts[i] : 0;
    int lane = t & 63, w = t >> 6;
    int x = v;
    #pragma unroll
    for (int off = 1; off < 64; off <<= 1) {
        int y = __shfl_up(x, off, 64);
        if (lane >= off) x += y;
    }
    __shared__ int wsum[4];
    __shared__ int woff[4];
    if (lane == 63) wsum[w] = x;
    __syncthreads();
    if (t == 0) {
        int s = 0;
        #pragma unroll
        for (int k = 0; k < 4; ++k) { woff[k] = s; s += wsum[k]; }
        blk_tot[b] = s;
    }
    __syncthreads();
    if (i < N_NODES) row_start[i] = x - v + woff[w];
}

__global__ __launch_bounds__(128) void scan_offsets_kernel(const int* __restrict__ blk_tot,
                                                           int* __restrict__ blk_off) {
    __shared__ int sd[128];
    int t = threadIdx.x;
    int v = (t < N_SCAN_BLOCKS) ? blk_tot[t] : 0;
    sd[t] = v;
    __syncthreads();
    #pragma unroll
    for (int off = 1; off < 128; off <<= 1) {
        int add = (t >= off) ? sd[t - off] : 0;
        __syncthreads();
        sd[t] += add;
        __syncthreads();
    }
    if (t < N_SCAN_BLOCKS) blk_off[t] = sd[t] - v;
}

__global__ __launch_bounds__(256) void scan_add_kernel(int* __restrict__ row_start,
                                                       const int* __restrict__ blk_off,
                                                       int* __restrict__ cursor) {
    int b = blockIdx.x, t = threadIdx.x;
    int i = b * 256 + t;
    if (i >= N_NODES) return;
    int r = row_start[i] + blk_off[b];
    row_start[i] = r;
    cursor[i] = r;
}

__global__ __launch_bounds__(256) void fill_kernel(const int* __restrict__ ei,
                                                   int* __restrict__ cursor,
                                                   int* __restrict__ src_csr,
                                                   int* __restrict__ edge_pos) {
    int e = blockIdx.x * 256 + threadIdx.x;
    if (e >= N_EDGES) return;
    int s = ei[e];
    int d = ei[N_EDGES + e];
    int pos = atomicAdd(&cursor[d], 1);
    src_csr[pos] = s;
    edge_pos[e] = pos;
}

// ---------------------------------------------------------------- w_eff[h][d] = sum_c We[d, h*64+c] * att_edge[h,c]
__global__ void weff_kernel(const float* __restrict__ We, const float* __restrict__ att_edge,
                            float* __restrict__ w_eff) {
    int t = threadIdx.x;          // 64 threads
    int hh = t >> 4, d = t & 15;
    float acc = 0.f;
    #pragma unroll 8
    for (int c = 0; c < HID; ++c)
        acc += We[d * HC + hh * HID + c] * att_edge[hh * HID + c];
    w_eff[hh * 16 + d] = acc;
}

// ---------------------------------------------------------------- MFMA GEMM: C16[M,256] = f16( A16[M,K] @ Wt16^T )
// BM=64, BN=256 (wave w = head w), BK=32, 16x16x32 f16 MFMA, f32 accum.
// LDS in fragment order: slot (group*64 + lane)*8 halfs -> lane-contiguous ds_read_b128.
// Fused epilogue: a_src/a_dst dots + fp16 C table store.
__global__ __launch_bounds__(256) void gemm16_kernel(const __half* __restrict__ A16,
                                                     const __half* __restrict__ Wt16,
                                                     __half* __restrict__ C16, int M, int K,
                                                     const float* __restrict__ att_src,
                                                     const float* __restrict__ att_dst,
                                                     float* __restrict__ a_src,
                                                     float* __restrict__ a_dst) {
    __shared__ __align__(16) _Float16 As[4 * 64 * 8];    // 4 KB
    __shared__ __align__(16) _Float16 Bs[16 * 64 * 8];   // 16 KB
    int t = threadIdx.x;
    int w = t >> 6, l = t & 63;
    int m0 = blockIdx.x * 64;
    f32x4 acc[4][4] = {};

    // A staging map: thread -> row r = t>>2, k-chunk q = t&3
    int ar = t >> 2, aq = t & 3;
    int am = m0 + ar;
    bool aok = am < M;
    const _Float16* agp = (const _Float16*)A16 + (size_t)(aok ? am : 0) * K + aq * 8;
    _Float16* awp = &As[(size_t)(((ar >> 4) * 64) + ((ar & 15) | (aq << 4))) * 8];
    // B staging map: thread -> n = t, 4 k-chunks
    const _Float16* bgp = (const _Float16*)Wt16 + (size_t)t * K;
    _Float16* bwp = &Bs[(size_t)((t >> 4) * 64 + (t & 15)) * 8];

    for (int kt = 0; kt < K; kt += 32) {
        f16x8 av = (f16x8)0;
        if (aok) av = *(const f16x8*)(agp + kt);
        *(f16x8*)awp = av;
        #pragma unroll
        for (int q = 0; q < 4; ++q)
            *(f16x8*)(bwp + (size_t)(q << 4) * 8) = *(const f16x8*)(bgp + kt + q * 8);
        __syncthreads();
        f16x8 af[4], bf[4];
        #pragma unroll
        for (int mi = 0; mi < 4; ++mi) af[mi] = *(const f16x8*)&As[(size_t)(mi * 64 + l) * 8];
        #pragma unroll
        for (int ni = 0; ni < 4; ++ni) bf[ni] = *(const f16x8*)&Bs[(size_t)((w * 4 + ni) * 64 + l) * 8];
        #pragma unroll
        for (int mi = 0; mi < 4; ++mi)
            #pragma unroll
            for (int ni = 0; ni < 4; ++ni)
                acc[mi][ni] = __builtin_amdgcn_mfma_f32_16x16x32_f16(af[mi], bf[ni], acc[mi][ni], 0, 0, 0);
        __syncthreads();
    }

    // C/D layout: col = w*64 + ni*16 + (l&15), row = m0 + mi*16 + (l>>4)*4 + reg
    int cg = l & 15, gg = l >> 4;
    float avs[4], avd[4];
    #pragma unroll
    for (int ni = 0; ni < 4; ++ni) {
        avs[ni] = att_src[w * 64 + ni * 16 + cg];
        avd[ni] = att_dst[w * 64 + ni * 16 + cg];
    }
    #pragma unroll
    for (int mi = 0; mi < 4; ++mi) {
        #pragma unroll
        for (int reg = 0; reg < 4; ++reg) {
            float ps = acc[mi][0][reg] * avs[0] + acc[mi][1][reg] * avs[1]
                     + acc[mi][2][reg] * avs[2] + acc[mi][3][reg] * avs[3];
            float pd = acc[mi][0][reg] * avd[0] + acc[mi][1][reg] * avd[1]
                     + acc[mi][2][reg] * avd[2] + acc[mi][3][reg] * avd[3];
            #pragma unroll
            for (int o = 1; o < 16; o <<= 1) {
                ps += __shfl_xor(ps, o, 64);
                pd += __shfl_xor(pd, o, 64);
            }
            int m = m0 + mi * 16 + gg * 4 + reg;
            if (cg == 0 && m < M) {
                a_src[(size_t)m * 4 + w] = ps;
                a_dst[(size_t)m * 4 + w] = pd;
            }
        }
        #pragma unroll
        for (int ni = 0; ni < 4; ++ni)
            #pragma unroll
            for (int reg = 0; reg < 4; ++reg) {
                int m = m0 + mi * 16 + gg * 4 + reg;
                if (m < M)
                    C16[(size_t)m * HC + w * 64 + ni * 16 + cg] = __float2half(acc[mi][ni][reg]);
            }
    }
}

// ---------------------------------------------------------------- per-edge raw attention logits -> CSR order
__global__ __launch_bounds__(256) void alpha_kernel(const int* __restrict__ ei,
                                                    const float* __restrict__ edge_attr,
                                                    const float* __restrict__ w_eff,
                                                    const float* __restrict__ a_src,
                                                    const float* __restrict__ a_dst,
                                                    const int* __restrict__ edge_pos,
                                                    float4* __restrict__ alpha_csr) {
    __shared__ float wsh[64];
    int t = threadIdx.x;
    if (t < 64) wsh[t] = w_eff[t];
    __syncthreads();
    int e = blockIdx.x * 256 + t;
    if (e >= N_EDGES) return;
    int s = ei[e], d = ei[N_EDGES + e];
    const float* ea = edge_attr + (size_t)e * EDGE_DIM;
    float x[16];
    #pragma unroll
    for (int i = 0; i < 16; i += 4) {
        float4 v = *(const float4*)(ea + i);
        x[i] = v.x; x[i + 1] = v.y; x[i + 2] = v.z; x[i + 3] = v.w;
    }
    float4 as = *(const float4*)(a_src + (size_t)s * 4);
    float4 ad = *(const float4*)(a_dst + (size_t)d * 4);
    float asv[4] = {as.x, as.y, as.z, as.w};
    float adv[4] = {ad.x, ad.y, ad.z, ad.w};
    float al[4];
    #pragma unroll
    for (int hh = 0; hh < 4; ++hh) {
        float acc = 0.f;
        #pragma unroll
        for (int i = 0; i < 16; ++i) acc += x[i] * wsh[hh * 16 + i];
        float v = asv[hh] + adv[hh] + acc;
        al[hh] = v > 0.f ? v : NEG_SLOPE * v;   // leaky_relu
    }
    alpha_csr[edge_pos[e]] = make_float4(al[0], al[1], al[2], al[3]);
}

// ---------------------------------------------------------------- aggregate: wave per node, softmax + fp16 gather, fp16 out
__global__ __launch_bounds__(256) void aggregate_kernel(const int* __restrict__ src_csr,
                                                        const float4* __restrict__ alpha_csr,
                                                        const int* __restrict__ row_start,
                                                        const int* __restrict__ counts,
                                                        const __half* __restrict__ h16,
                                                        const float* __restrict__ bias,
                                                        __half* __restrict__ out16) {
    int wid = threadIdx.x >> 6, lane = threadIdx.x & 63;
    int n = blockIdx.x * 4 + wid;
    if (n >= N_NODES) return;
    int start = row_start[n];
    int deg = counts[n];
    const float4* ap = alpha_csr + start;
    const int* sp = src_csr + start;

    float m0 = -INFINITY, m1 = -INFINITY, m2 = -INFINITY, m3 = -INFINITY;
    for (int i = lane; i < deg; i += 64) {
        float4 a = ap[i];
        m0 = fmaxf(m0, a.x); m1 = fmaxf(m1, a.y);
        m2 = fmaxf(m2, a.z); m3 = fmaxf(m3, a.w);
    }
    #pragma unroll
    for (int o = 32; o > 0; o >>= 1) {
        m0 = fmaxf(m0, __shfl_xor(m0, o, 64));
        m1 = fmaxf(m1, __shfl_xor(m1, o, 64));
        m2 = fmaxf(m2, __shfl_xor(m2, o, 64));
        m3 = fmaxf(m3, __shfl_xor(m3, o, 64));
    }
    bool lo = (lane < 32);
    float mA = lo ? m0 : m1;
    float mB = lo ? m2 : m3;

    float aAx = 0.f, aAy = 0.f, aBx = 0.f, aBy = 0.f;
    float dA = 0.f, dB = 0.f;
    int s_next = (deg > 0) ? sp[0] : 0;
    #pragma unroll 2
    for (int i = 0; i < deg; ++i) {
        int s = s_next;
        if (i + 1 < deg) s_next = sp[i + 1];
        float4 a = ap[i];
        float eA = __expf((lo ? a.x : a.y) - mA);
        float eB = __expf((lo ? a.z : a.w) - mB);
        dA += eA; dB += eB;
        const __half2* hr = (const __half2*)(h16 + (size_t)s * HC);
        __half2 vA = hr[lane];
        __half2 vB = hr[64 + lane];
        float2 fA = __half22float2(vA);
        float2 fB = __half22float2(vB);
        aAx += eA * fA.x; aAy += eA * fA.y;
        aBx += eB * fB.x; aBy += eB * fB.y;
    }
    float2 b01 = *(const float2*)(bias + 2 * lane);
    float2 b23 = *(const float2*)(bias + 128 + 2 * lane);
    float invA = 1.f / (dA + EPSF);
    float invB = 1.f / (dB + EPSF);
    float r0 = fmaxf(aAx * invA + b01.x, 0.f);
    float r1 = fmaxf(aAy * invA + b01.y, 0.f);
    float r2 = fmaxf(aBx * invB + b23.x, 0.f);
    float r3 = fmaxf(aBy * invB + b23.y, 0.f);
    __half* o = out16 + (size_t)n * HC;
    *(__half2*)(o + 2 * lane)       = __floats2half2_rn(r0, r1);
    *(__half2*)(o + 128 + 2 * lane) = __floats2half2_rn(r2, r3);
}

// ---------------------------------------------------------------- pooling (batch is sorted), fp16 input
#define NPB 100
__global__ __launch_bounds__(256) void pool_kernel(const __half* __restrict__ h,
                                                   const int* __restrict__ batch,
                                                   float* __restrict__ pooled,
                                                   int* __restrict__ gcounts) {
    int t = threadIdx.x;
    int n0 = blockIdx.x * NPB;
    int n1 = n0 + NPB;
    if (n1 > N_NODES) n1 = N_NODES;
    if (n0 >= N_NODES) return;
    int cur = batch[n0];
    float acc = 0.f;
    int cnt = 0;
    for (int n = n0; n < n1; ++n) {
        int g = batch[n];
        if (g != cur) {
            atomicAdd(&pooled[cur * HC + t], acc);
            if (t == 0) atomicAdd(&gcounts[cur], cnt);
            acc = 0.f; cnt = 0; cur = g;
        }
        acc += __half2float(h[(size_t)n * HC + t]);
        cnt++;
    }
    atomicAdd(&pooled[cur * HC + t], acc);
    if (t == 0) atomicAdd(&gcounts[cur], cnt);
}

__global__ __launch_bounds__(256) void finalize_kernel(const float* __restrict__ pooled,
                                                       const int* __restrict__ gcounts,
                                                       float* __restrict__ out) {
    int g = blockIdx.x, t = threadIdx.x;
    float c = (float)(gcounts[g] > 1 ? gcounts[g] : 1);
    out[g * HC + t] = tanhf(pooled[g * HC + t] / c);
}

// ---------------------------------------------------------------- launch
extern "C" void kernel_launch(void* const* d_in, const int* in_sizes, int n_in,
                              void* d_out, int out_size, void* d_ws, size_t ws_size,
                              hipStream_t stream) {
    const float* x         = (const float*)d_in[0];
    const int*   ei        = (const int*)d_in[1];
    const float* edge_attr = (const float*)d_in[2];
    const int*   batch     = (const int*)d_in[3];
    const float* Wl[3]  = {(const float*)d_in[4],  (const float*)d_in[10], (const float*)d_in[16]};
    const float* Wel[3] = {(const float*)d_in[5],  (const float*)d_in[11], (const float*)d_in[17]};
    const float* asl[3] = {(const float*)d_in[6],  (const float*)d_in[12], (const float*)d_in[18]};
    const float* adl[3] = {(const float*)d_in[7],  (const float*)d_in[13], (const float*)d_in[19]};
    const float* ael[3] = {(const float*)d_in[8],  (const float*)d_in[14], (const float*)d_in[20]};
    const float* bl[3]  = {(const float*)d_in[9],  (const float*)d_in[15], (const float*)d_in[21]};
    float* out = (float*)d_out;

    // workspace carve (256B aligned)
    char* p = (char*)d_ws;
    auto alloc = [&](size_t bytes) -> void* {
        void* r = (void*)p;
        p += (bytes + 255) & ~(size_t)255;
        return r;
    };
    __half* x16       = (__half*)alloc((size_t)N_NODES * OBS * 2);
    __half* hA16      = (__half*)alloc((size_t)N_NODES * HC * 2);
    __half* hB16      = (__half*)alloc((size_t)N_NODES * HC * 2);
    __half* wt0       = (__half*)alloc((size_t)HC * OBS * 2);
    __half* wt1       = (__half*)alloc((size_t)HC * HC * 2);
    __half* wt2       = (__half*)alloc((size_t)HC * HC * 2);
    float* a_src      = (float*)alloc((size_t)N_NODES * 4 * 4);
    float* a_dst      = (float*)alloc((size_t)N_NODES * 4 * 4);
    float4* alpha_csr = (float4*)alloc((size_t)N_EDGES * 16);
    int* counts       = (int*)alloc((size_t)N_NODES * 4);
    int* row_start    = (int*)alloc((size_t)N_NODES * 4);
    int* cursor       = (int*)alloc((size_t)N_NODES * 4);
    int* src_csr      = (int*)alloc((size_t)N_EDGES * 4);
    int* edge_pos     = (int*)alloc((size_t)N_EDGES * 4);
    float* w_eff      = (float*)alloc(64 * 4);
    float* pooled     = (float*)alloc((size_t)N_GRAPHS * HC * 4);
    int* gcounts      = (int*)alloc((size_t)N_GRAPHS * 4);
    int* blk_tot      = (int*)alloc((size_t)N_SCAN_BLOCKS * 4);
    int* blk_off      = (int*)alloc((size_t)N_SCAN_BLOCKS * 4);
    const __half* wtl[3] = {wt0, wt1, wt2};

    // zero scratch that accumulates
    zero_kernel<<<(N_NODES + 255) / 256, 256, 0, stream>>>((unsigned int*)counts, N_NODES);
    zero_kernel<<<(N_GRAPHS * HC + 255) / 256, 256, 0, stream>>>((unsigned int*)pooled, N_GRAPHS * HC);
    zero_kernel<<<1, 256, 0, stream>>>((unsigned int*)gcounts, N_GRAPHS);

    // input/weight conversions
    cvt_kernel<<<(N_NODES * OBS / 4 + 255) / 256, 256, 0, stream>>>(x, x16, N_NODES * OBS);
    wt_kernel<<<OBS, 256, 0, stream>>>(Wl[0], wt0, OBS);
    wt_kernel<<<HC, 256, 0, stream>>>(Wl[1], wt1, HC);
    wt_kernel<<<HC, 256, 0, stream>>>(Wl[2], wt2, HC);

    // CSR build over dst (parallel two-level scan)
    count_kernel<<<N_EDGES / 256, 256, 0, stream>>>(ei, counts);
    scan_local_kernel<<<N_SCAN_BLOCKS, 256, 0, stream>>>(counts, row_start, blk_tot);
    scan_offsets_kernel<<<1, 128, 0, stream>>>(blk_tot, blk_off);
    scan_add_kernel<<<N_SCAN_BLOCKS, 256, 0, stream>>>(row_start, blk_off, cursor);
    fill_kernel<<<N_EDGES / 256, 256, 0, stream>>>(ei, cursor, src_csr, edge_pos);

    const __half* cur_in = x16;
    int K = OBS;
    for (int l = 0; l < 3; ++l) {
        gemm16_kernel<<<(N_NODES + 63) / 64, 256, 0, stream>>>(cur_in, wtl[l], hA16, N_NODES, K,
                                                               asl[l], adl[l], a_src, a_dst);
        weff_kernel<<<1, 64, 0, stream>>>(Wel[l], ael[l], w_eff);
        alpha_kernel<<<N_EDGES / 256, 256, 0, stream>>>(ei, edge_attr, w_eff, a_src, a_dst,
                                                        edge_pos, alpha_csr);
        aggregate_kernel<<<(N_NODES + 3) / 4, 256, 0, stream>>>(src_csr, alpha_csr, row_start,
                                                                counts, hA16, bl[l], hB16);
        cur_in = hB16;
        K = HC;
    }

    // global mean pool + tanh
    pool_kernel<<<(N_NODES + NPB - 1) / NPB, 256, 0, stream>>>(hB16, batch, pooled, gcounts);
    finalize_kernel<<<N_GRAPHS, 256, 0, stream>>>(pooled, gcounts, out);
}

// Round 6
// 280.744 us; speedup vs baseline: 1.1052x; 1.0008x over previous
//
#include <hip/hip_runtime.h>
#include <hip/hip_bf16.h>
#include <hip/hip_fp16.h>
#include <math.h>

#define N_NODES 20000
#define N_EDGES 320000
#define N_GRAPHS 64
#define OBS 64
#define EDGE_DIM 16
#define HEADS 4
#define HID 64
#define HC 256            // HEADS*HID
#define NEG_SLOPE 0.2f
#define EPSF 1e-16f
#define N_SCAN_BLOCKS ((N_NODES + 255) / 256)   // 79

typedef _Float16 f16x8 __attribute__((ext_vector_type(8)));
typedef float f32x4 __attribute__((ext_vector_type(4)));

// ---------------------------------------------------------------- utilities
__global__ __launch_bounds__(256) void zero_kernel(unsigned int* __restrict__ p, int n) {
    int i = blockIdx.x * 256 + threadIdx.x;
    if (i < n) p[i] = 0u;
}

// f32 -> f16 convert (n divisible by 4)
__global__ __launch_bounds__(256) void cvt_kernel(const float* __restrict__ in,
                                                  __half* __restrict__ out, int n) {
    int i = (blockIdx.x * 256 + threadIdx.x) * 4;
    if (i >= n) return;
    float4 v = *(const float4*)(in + i);
    *(__half2*)(out + i)     = __floats2half2_rn(v.x, v.y);
    *(__half2*)(out + i + 2) = __floats2half2_rn(v.z, v.w);
}

// Wt[n][k] = (f16) W[k][n]   (grid = K blocks, 256 threads)
__global__ __launch_bounds__(256) void wt_kernel(const float* __restrict__ W,
                                                 __half* __restrict__ Wt, int K) {
    int k = blockIdx.x;
    int n = threadIdx.x;
    Wt[(size_t)n * K + k] = __float2half(W[(size_t)k * HC + n]);
}

// ---------------------------------------------------------------- CSR build
__global__ __launch_bounds__(256) void count_kernel(const int* __restrict__ ei, int* __restrict__ counts) {
    int e = blockIdx.x * 256 + threadIdx.x;
    if (e >= N_EDGES) return;
    atomicAdd(&counts[ei[N_EDGES + e]], 1);
}

__global__ __launch_bounds__(256) void scan_local_kernel(const int* __restrict__ counts,
                                                         int* __restrict__ row_start,
                                                         int* __restrict__ blk_tot) {
    int b = blockIdx.x, t = threadIdx.x;
    int i = b * 256 + t;
    int v = (i < N_NODES) ? counts[i] : 0;
    int lane = t & 63, w = t >> 6;
    int x = v;
    #pragma unroll
    for (int off = 1; off < 64; off <<= 1) {
        int y = __shfl_up(x, off, 64);
        if (lane >= off) x += y;
    }
    __shared__ int wsum[4];
    __shared__ int woff[4];
    if (lane == 63) wsum[w] = x;
    __syncthreads();
    if (t == 0) {
        int s = 0;
        #pragma unroll
        for (int k = 0; k < 4; ++k) { woff[k] = s; s += wsum[k]; }
        blk_tot[b] = s;
    }
    __syncthreads();
    if (i < N_NODES) row_start[i] = x - v + woff[w];
}

__global__ __launch_bounds__(128) void scan_offsets_kernel(const int* __restrict__ blk_tot,
                                                           int* __restrict__ blk_off) {
    __shared__ int sd[128];
    int t = threadIdx.x;
    int v = (t < N_SCAN_BLOCKS) ? blk_tot[t] : 0;
    sd[t] = v;
    __syncthreads();
    #pragma unroll
    for (int off = 1; off < 128; off <<= 1) {
        int add = (t >= off) ? sd[t - off] : 0;
        __syncthreads();
        sd[t] += add;
        __syncthreads();
    }
    if (t < N_SCAN_BLOCKS) blk_off[t] = sd[t] - v;
}

__global__ __launch_bounds__(256) void scan_add_kernel(int* __restrict__ row_start,
                                                       const int* __restrict__ blk_off,
                                                       int* __restrict__ cursor) {
    int b = blockIdx.x, t = threadIdx.x;
    int i = b * 256 + t;
    if (i >= N_NODES) return;
    int r = row_start[i] + blk_off[b];
    row_start[i] = r;
    cursor[i] = r;
}

__global__ __launch_bounds__(256) void fill_kernel(const int* __restrict__ ei,
                                                   int* __restrict__ cursor,
                                                   int* __restrict__ src_csr,
                                                   int* __restrict__ edge_pos) {
    int e = blockIdx.x * 256 + threadIdx.x;
    if (e >= N_EDGES) return;
    int s = ei[e];
    int d = ei[N_EDGES + e];
    int pos = atomicAdd(&cursor[d], 1);
    src_csr[pos] = s;
    edge_pos[e] = pos;
}

// ---------------------------------------------------------------- w_eff[h][d] = sum_c We[d, h*64+c] * att_edge[h,c]
__global__ void weff_kernel(const float* __restrict__ We, const float* __restrict__ att_edge,
                            float* __restrict__ w_eff) {
    int t = threadIdx.x;          // 64 threads
    int hh = t >> 4, d = t & 15;
    float acc = 0.f;
    #pragma unroll 8
    for (int c = 0; c < HID; ++c)
        acc += We[d * HC + hh * HID + c] * att_edge[hh * HID + c];
    w_eff[hh * 16 + d] = acc;
}

// ---------------------------------------------------------------- MFMA GEMM: C16[M,256] = f16( A16[M,K] @ Wt16^T )
// BM=64, BN=256 (wave w = head w), K = NKT*32 compile-time.
// A staged ONCE to LDS in fragment order (1 barrier); B read direct from
// global (Wt is L2-resident, 128KB shared by all blocks); C repacked via LDS
// for fully-coalesced 1KB/wave stores. Fused a_src/a_dst epilogue.
template <int NKT>
__global__ __launch_bounds__(256) void gemm16_kernel(const __half* __restrict__ A16,
                                                     const __half* __restrict__ Wt16,
                                                     __half* __restrict__ C16, int M,
                                                     const float* __restrict__ att_src,
                                                     const float* __restrict__ att_dst,
                                                     float* __restrict__ a_src,
                                                     float* __restrict__ a_dst) {
    constexpr int K = NKT * 32;
    __shared__ __align__(16) _Float16 lds[64 * 264];   // 33 KB: As (<=32KB) then Cs
    int t = threadIdx.x;
    int w = t >> 6, l = t & 63;
    int cg = l & 15, gg = l >> 4;
    int m0 = blockIdx.x * 64;

    // ---- stage A block (64 rows x K halfs) into LDS, fragment order.
    // slot f = t encodes row=(t>>6)*16+(t&15), k8=(t>>4)&3; write addr lane-contiguous.
    {
        int row = (t >> 6) * 16 + (t & 15);
        int k8 = (t >> 4) & 3;
        int rg = m0 + row;
        if (rg >= M) rg = M - 1;                       // clamp: garbage rows never stored
        const _Float16* ag = (const _Float16*)A16 + (size_t)rg * K + k8 * 8;
        f16x8 tmp[NKT];
        #pragma unroll
        for (int j = 0; j < NKT; ++j) tmp[j] = *(const f16x8*)(ag + j * 32);
        #pragma unroll
        for (int j = 0; j < NKT; ++j) *(f16x8*)&lds[(size_t)(j * 256 + t) * 8] = tmp[j];
    }
    __syncthreads();

    // ---- main loop: B from global (L2), A fragments from LDS, 16 MFMA / kt
    f32x4 acc[4][4] = {};
    const _Float16* bg = (const _Float16*)Wt16 + (size_t)(w * 64 + cg) * K + gg * 8;
    #pragma unroll 2
    for (int kt = 0; kt < NKT; ++kt) {
        f16x8 bf[4], af[4];
        #pragma unroll
        for (int ni = 0; ni < 4; ++ni)
            bf[ni] = *(const f16x8*)(bg + (size_t)(ni * 16) * K + kt * 32);
        #pragma unroll
        for (int mi = 0; mi < 4; ++mi)
            af[mi] = *(const f16x8*)&lds[(size_t)(kt * 256 + mi * 64 + l) * 8];
        #pragma unroll
        for (int mi = 0; mi < 4; ++mi)
            #pragma unroll
            for (int ni = 0; ni < 4; ++ni)
                acc[mi][ni] = __builtin_amdgcn_mfma_f32_16x16x32_f16(af[mi], bf[ni], acc[mi][ni], 0, 0, 0);
    }

    // ---- fused attdot epilogue (f32 acc); C/D: col=w*64+ni*16+cg, row=mi*16+gg*4+reg
    {
        float avs[4], avd[4];
        #pragma unroll
        for (int ni = 0; ni < 4; ++ni) {
            avs[ni] = att_src[w * 64 + ni * 16 + cg];
            avd[ni] = att_dst[w * 64 + ni * 16 + cg];
        }
        #pragma unroll
        for (int mi = 0; mi < 4; ++mi)
            #pragma unroll
            for (int reg = 0; reg < 4; ++reg) {
                float ps = acc[mi][0][reg] * avs[0] + acc[mi][1][reg] * avs[1]
                         + acc[mi][2][reg] * avs[2] + acc[mi][3][reg] * avs[3];
                float pd = acc[mi][0][reg] * avd[0] + acc[mi][1][reg] * avd[1]
                         + acc[mi][2][reg] * avd[2] + acc[mi][3][reg] * avd[3];
                #pragma unroll
                for (int o = 1; o < 16; o <<= 1) {
                    ps += __shfl_xor(ps, o, 64);
                    pd += __shfl_xor(pd, o, 64);
                }
                int m = m0 + mi * 16 + gg * 4 + reg;
                if (cg == 0 && m < M) {
                    a_src[(size_t)m * 4 + w] = ps;
                    a_dst[(size_t)m * 4 + w] = pd;
                }
            }
    }

    // ---- C repack: acc -> LDS f16 tile (stride 264, 2-way banks max) -> coalesced store
    __syncthreads();   // all waves done reading As
    #pragma unroll
    for (int mi = 0; mi < 4; ++mi)
        #pragma unroll
        for (int ni = 0; ni < 4; ++ni)
            #pragma unroll
            for (int reg = 0; reg < 4; ++reg) {
                int row = mi * 16 + gg * 4 + reg;
                int col = w * 64 + ni * 16 + cg;
                lds[row * 264 + col] = (_Float16)acc[mi][ni][reg];
            }
    __syncthreads();
    #pragma unroll
    for (int i = 0; i < 8; ++i) {
        int g = i * 256 + t;
        int row = g >> 5, cw = g & 31;
        int m = m0 + row;
        if (m < M) {
            f16x8 v = *(const f16x8*)&lds[row * 264 + cw * 8];
            *(f16x8*)((_Float16*)C16 + (size_t)m * HC + cw * 8) = v;
        }
    }
}

// ---------------------------------------------------------------- per-edge raw attention logits -> CSR order
__global__ __launch_bounds__(256) void alpha_kernel(const int* __restrict__ ei,
                                                    const float* __restrict__ edge_attr,
                                                    const float* __restrict__ w_eff,
                                                    const float* __restrict__ a_src,
                                                    const float* __restrict__ a_dst,
                                                    const int* __restrict__ edge_pos,
                                                    float4* __restrict__ alpha_csr) {
    __shared__ float wsh[64];
    int t = threadIdx.x;
    if (t < 64) wsh[t] = w_eff[t];
    __syncthreads();
    int e = blockIdx.x * 256 + t;
    if (e >= N_EDGES) return;
    int s = ei[e], d = ei[N_EDGES + e];
    const float* ea = edge_attr + (size_t)e * EDGE_DIM;
    float x[16];
    #pragma unroll
    for (int i = 0; i < 16; i += 4) {
        float4 v = *(const float4*)(ea + i);
        x[i] = v.x; x[i + 1] = v.y; x[i + 2] = v.z; x[i + 3] = v.w;
    }
    float4 as = *(const float4*)(a_src + (size_t)s * 4);
    float4 ad = *(const float4*)(a_dst + (size_t)d * 4);
    float asv[4] = {as.x, as.y, as.z, as.w};
    float adv[4] = {ad.x, ad.y, ad.z, ad.w};
    float al[4];
    #pragma unroll
    for (int hh = 0; hh < 4; ++hh) {
        float acc = 0.f;
        #pragma unroll
        for (int i = 0; i < 16; ++i) acc += x[i] * wsh[hh * 16 + i];
        float v = asv[hh] + adv[hh] + acc;
        al[hh] = v > 0.f ? v : NEG_SLOPE * v;   // leaky_relu
    }
    alpha_csr[edge_pos[e]] = make_float4(al[0], al[1], al[2], al[3]);
}

// ---------------------------------------------------------------- aggregate: wave per node, softmax + fp16 gather, fp16 out
__global__ __launch_bounds__(256) void aggregate_kernel(const int* __restrict__ src_csr,
                                                        const float4* __restrict__ alpha_csr,
                                                        const int* __restrict__ row_start,
                                                        const int* __restrict__ counts,
                                                        const __half* __restrict__ h16,
                                                        const float* __restrict__ bias,
                                                        __half* __restrict__ out16) {
    int wid = threadIdx.x >> 6, lane = threadIdx.x & 63;
    int n = blockIdx.x * 4 + wid;
    if (n >= N_NODES) return;
    int start = row_start[n];
    int deg = counts[n];
    const float4* ap = alpha_csr + start;
    const int* sp = src_csr + start;

    float m0 = -INFINITY, m1 = -INFINITY, m2 = -INFINITY, m3 = -INFINITY;
    for (int i = lane; i < deg; i += 64) {
        float4 a = ap[i];
        m0 = fmaxf(m0, a.x); m1 = fmaxf(m1, a.y);
        m2 = fmaxf(m2, a.z); m3 = fmaxf(m3, a.w);
    }
    #pragma unroll
    for (int o = 32; o > 0; o >>= 1) {
        m0 = fmaxf(m0, __shfl_xor(m0, o, 64));
        m1 = fmaxf(m1, __shfl_xor(m1, o, 64));
        m2 = fmaxf(m2, __shfl_xor(m2, o, 64));
        m3 = fmaxf(m3, __shfl_xor(m3, o, 64));
    }
    bool lo = (lane < 32);
    float mA = lo ? m0 : m1;
    float mB = lo ? m2 : m3;

    float aAx = 0.f, aAy = 0.f, aBx = 0.f, aBy = 0.f;
    float dA = 0.f, dB = 0.f;
    int s_next = (deg > 0) ? sp[0] : 0;
    #pragma unroll 2
    for (int i = 0; i < deg; ++i) {
        int s = s_next;
        if (i + 1 < deg) s_next = sp[i + 1];
        float4 a = ap[i];
        float eA = __expf((lo ? a.x : a.y) - mA);
        float eB = __expf((lo ? a.z : a.w) - mB);
        dA += eA; dB += eB;
        const __half2* hr = (const __half2*)(h16 + (size_t)s * HC);
        __half2 vA = hr[lane];
        __half2 vB = hr[64 + lane];
        float2 fA = __half22float2(vA);
        float2 fB = __half22float2(vB);
        aAx += eA * fA.x; aAy += eA * fA.y;
        aBx += eB * fB.x; aBy += eB * fB.y;
    }
    float2 b01 = *(const float2*)(bias + 2 * lane);
    float2 b23 = *(const float2*)(bias + 128 + 2 * lane);
    float invA = 1.f / (dA + EPSF);
    float invB = 1.f / (dB + EPSF);
    float r0 = fmaxf(aAx * invA + b01.x, 0.f);
    float r1 = fmaxf(aAy * invA + b01.y, 0.f);
    float r2 = fmaxf(aBx * invB + b23.x, 0.f);
    float r3 = fmaxf(aBy * invB + b23.y, 0.f);
    __half* o = out16 + (size_t)n * HC;
    *(__half2*)(o + 2 * lane)       = __floats2half2_rn(r0, r1);
    *(__half2*)(o + 128 + 2 * lane) = __floats2half2_rn(r2, r3);
}

// ---------------------------------------------------------------- pooling (batch is sorted), fp16 input
#define NPB 100
__global__ __launch_bounds__(256) void pool_kernel(const __half* __restrict__ h,
                                                   const int* __restrict__ batch,
                                                   float* __restrict__ pooled,
                                                   int* __restrict__ gcounts) {
    int t = threadIdx.x;
    int n0 = blockIdx.x * NPB;
    int n1 = n0 + NPB;
    if (n1 > N_NODES) n1 = N_NODES;
    if (n0 >= N_NODES) return;
    int cur = batch[n0];
    float acc = 0.f;
    int cnt = 0;
    for (int n = n0; n < n1; ++n) {
        int g = batch[n];
        if (g != cur) {
            atomicAdd(&pooled[cur * HC + t], acc);
            if (t == 0) atomicAdd(&gcounts[cur], cnt);
            acc = 0.f; cnt = 0; cur = g;
        }
        acc += __half2float(h[(size_t)n * HC + t]);
        cnt++;
    }
    atomicAdd(&pooled[cur * HC + t], acc);
    if (t == 0) atomicAdd(&gcounts[cur], cnt);
}

__global__ __launch_bounds__(256) void finalize_kernel(const float* __restrict__ pooled,
                                                       const int* __restrict__ gcounts,
                                                       float* __restrict__ out) {
    int g = blockIdx.x, t = threadIdx.x;
    float c = (float)(gcounts[g] > 1 ? gcounts[g] : 1);
    out[g * HC + t] = tanhf(pooled[g * HC + t] / c);
}

// ---------------------------------------------------------------- launch
extern "C" void kernel_launch(void* const* d_in, const int* in_sizes, int n_in,
                              void* d_out, int out_size, void* d_ws, size_t ws_size,
                              hipStream_t stream) {
    const float* x         = (const float*)d_in[0];
    const int*   ei        = (const int*)d_in[1];
    const float* edge_attr = (const float*)d_in[2];
    const int*   batch     = (const int*)d_in[3];
    const float* Wl[3]  = {(const float*)d_in[4],  (const float*)d_in[10], (const float*)d_in[16]};
    const float* Wel[3] = {(const float*)d_in[5],  (const float*)d_in[11], (const float*)d_in[17]};
    const float* asl[3] = {(const float*)d_in[6],  (const float*)d_in[12], (const float*)d_in[18]};
    const float* adl[3] = {(const float*)d_in[7],  (const float*)d_in[13], (const float*)d_in[19]};
    const float* ael[3] = {(const float*)d_in[8],  (const float*)d_in[14], (const float*)d_in[20]};
    const float* bl[3]  = {(const float*)d_in[9],  (const float*)d_in[15], (const float*)d_in[21]};
    float* out = (float*)d_out;

    // workspace carve (256B aligned)
    char* p = (char*)d_ws;
    auto alloc = [&](size_t bytes) -> void* {
        void* r = (void*)p;
        p += (bytes + 255) & ~(size_t)255;
        return r;
    };
    __half* x16       = (__half*)alloc((size_t)N_NODES * OBS * 2);
    __half* hA16      = (__half*)alloc((size_t)N_NODES * HC * 2);
    __half* hB16      = (__half*)alloc((size_t)N_NODES * HC * 2);
    __half* wt0       = (__half*)alloc((size_t)HC * OBS * 2);
    __half* wt1       = (__half*)alloc((size_t)HC * HC * 2);
    __half* wt2       = (__half*)alloc((size_t)HC * HC * 2);
    float* a_src      = (float*)alloc((size_t)N_NODES * 4 * 4);
    float* a_dst      = (float*)alloc((size_t)N_NODES * 4 * 4);
    float4* alpha_csr = (float4*)alloc((size_t)N_EDGES * 16);
    int* counts       = (int*)alloc((size_t)N_NODES * 4);
    int* row_start    = (int*)alloc((size_t)N_NODES * 4);
    int* cursor       = (int*)alloc((size_t)N_NODES * 4);
    int* src_csr      = (int*)alloc((size_t)N_EDGES * 4);
    int* edge_pos     = (int*)alloc((size_t)N_EDGES * 4);
    float* w_eff      = (float*)alloc(64 * 4);
    float* pooled     = (float*)alloc((size_t)N_GRAPHS * HC * 4);
    int* gcounts      = (int*)alloc((size_t)N_GRAPHS * 4);
    int* blk_tot      = (int*)alloc((size_t)N_SCAN_BLOCKS * 4);
    int* blk_off      = (int*)alloc((size_t)N_SCAN_BLOCKS * 4);

    // zero scratch that accumulates
    zero_kernel<<<(N_NODES + 255) / 256, 256, 0, stream>>>((unsigned int*)counts, N_NODES);
    zero_kernel<<<(N_GRAPHS * HC + 255) / 256, 256, 0, stream>>>((unsigned int*)pooled, N_GRAPHS * HC);
    zero_kernel<<<1, 256, 0, stream>>>((unsigned int*)gcounts, N_GRAPHS);

    // input/weight conversions
    cvt_kernel<<<(N_NODES * OBS / 4 + 255) / 256, 256, 0, stream>>>(x, x16, N_NODES * OBS);
    wt_kernel<<<OBS, 256, 0, stream>>>(Wl[0], wt0, OBS);
    wt_kernel<<<HC, 256, 0, stream>>>(Wl[1], wt1, HC);
    wt_kernel<<<HC, 256, 0, stream>>>(Wl[2], wt2, HC);

    // CSR build over dst (parallel two-level scan)
    count_kernel<<<N_EDGES / 256, 256, 0, stream>>>(ei, counts);
    scan_local_kernel<<<N_SCAN_BLOCKS, 256, 0, stream>>>(counts, row_start, blk_tot);
    scan_offsets_kernel<<<1, 128, 0, stream>>>(blk_tot, blk_off);
    scan_add_kernel<<<N_SCAN_BLOCKS, 256, 0, stream>>>(row_start, blk_off, cursor);
    fill_kernel<<<N_EDGES / 256, 256, 0, stream>>>(ei, cursor, src_csr, edge_pos);

    const int ngrid = (N_NODES + 63) / 64;
    const __half* wtl[3] = {wt0, wt1, wt2};
    const __half* cur_in = x16;
    for (int l = 0; l < 3; ++l) {
        if (l == 0)
            gemm16_kernel<2><<<ngrid, 256, 0, stream>>>(cur_in, wtl[l], hA16, N_NODES,
                                                        asl[l], adl[l], a_src, a_dst);
        else
            gemm16_kernel<8><<<ngrid, 256, 0, stream>>>(cur_in, wtl[l], hA16, N_NODES,
                                                        asl[l], adl[l], a_src, a_dst);
        weff_kernel<<<1, 64, 0, stream>>>(Wel[l], ael[l], w_eff);
        alpha_kernel<<<N_EDGES / 256, 256, 0, stream>>>(ei, edge_attr, w_eff, a_src, a_dst,
                                                        edge_pos, alpha_csr);
        aggregate_kernel<<<(N_NODES + 3) / 4, 256, 0, stream>>>(src_csr, alpha_csr, row_start,
                                                                counts, hA16, bl[l], hB16);
        cur_in = hB16;
    }

    // global mean pool + tanh
    pool_kernel<<<(N_NODES + NPB - 1) / NPB, 256, 0, stream>>>(hB16, batch, pooled, gcounts);
    finalize_kernel<<<N_GRAPHS, 256, 0, stream>>>(pooled, gcounts, out);
}

// Round 7
// 279.953 us; speedup vs baseline: 1.1083x; 1.0028x over previous
//
#include <hip/hip_runtime.h>
#include <hip/hip_bf16.h>
#include <hip/hip_fp16.h>
#include <math.h>

#define N_NODES 20000
#define N_EDGES 320000
#define N_GRAPHS 64
#define OBS 64
#define EDGE_DIM 16
#define HEADS 4
#define HID 64
#define HC 256            // HEADS*HID
#define NEG_SLOPE 0.2f
#define EPSF 1e-16f
#define N_SCAN_BLOCKS ((N_NODES + 255) / 256)   // 79

typedef _Float16 f16x8 __attribute__((ext_vector_type(8)));
typedef float f32x4 __attribute__((ext_vector_type(4)));

// ---------------------------------------------------------------- utilities
__global__ __launch_bounds__(256) void zero_kernel(unsigned int* __restrict__ p, int n) {
    int i = blockIdx.x * 256 + threadIdx.x;
    if (i < n) p[i] = 0u;
}

// f32 -> f16 convert (n divisible by 4)
__global__ __launch_bounds__(256) void cvt_kernel(const float* __restrict__ in,
                                                  __half* __restrict__ out, int n) {
    int i = (blockIdx.x * 256 + threadIdx.x) * 4;
    if (i >= n) return;
    float4 v = *(const float4*)(in + i);
    *(__half2*)(out + i)     = __floats2half2_rn(v.x, v.y);
    *(__half2*)(out + i + 2) = __floats2half2_rn(v.z, v.w);
}

// Wt[n][k] = (f16) W[k][n]   (grid = K blocks, 256 threads)
__global__ __launch_bounds__(256) void wt_kernel(const float* __restrict__ W,
                                                 __half* __restrict__ Wt, int K) {
    int k = blockIdx.x;
    int n = threadIdx.x;
    Wt[(size_t)n * K + k] = __float2half(W[(size_t)k * HC + n]);
}

// ---------------------------------------------------------------- CSR build
__global__ __launch_bounds__(256) void count_kernel(const int* __restrict__ ei, int* __restrict__ counts) {
    int e = blockIdx.x * 256 + threadIdx.x;
    if (e >= N_EDGES) return;
    atomicAdd(&counts[ei[N_EDGES + e]], 1);
}

__global__ __launch_bounds__(256) void scan_local_kernel(const int* __restrict__ counts,
                                                         int* __restrict__ row_start,
                                                         int* __restrict__ blk_tot) {
    int b = blockIdx.x, t = threadIdx.x;
    int i = b * 256 + t;
    int v = (i < N_NODES) ? counts[i] : 0;
    int lane = t & 63, w = t >> 6;
    int x = v;
    #pragma unroll
    for (int off = 1; off < 64; off <<= 1) {
        int y = __shfl_up(x, off, 64);
        if (lane >= off) x += y;
    }
    __shared__ int wsum[4];
    __shared__ int woff[4];
    if (lane == 63) wsum[w] = x;
    __syncthreads();
    if (t == 0) {
        int s = 0;
        #pragma unroll
        for (int k = 0; k < 4; ++k) { woff[k] = s; s += wsum[k]; }
        blk_tot[b] = s;
    }
    __syncthreads();
    if (i < N_NODES) row_start[i] = x - v + woff[w];
}

__global__ __launch_bounds__(128) void scan_offsets_kernel(const int* __restrict__ blk_tot,
                                                           int* __restrict__ blk_off) {
    __shared__ int sd[128];
    int t = threadIdx.x;
    int v = (t < N_SCAN_BLOCKS) ? blk_tot[t] : 0;
    sd[t] = v;
    __syncthreads();
    #pragma unroll
    for (int off = 1; off < 128; off <<= 1) {
        int add = (t >= off) ? sd[t - off] : 0;
        __syncthreads();
        sd[t] += add;
        __syncthreads();
    }
    if (t < N_SCAN_BLOCKS) blk_off[t] = sd[t] - v;
}

__global__ __launch_bounds__(256) void scan_add_kernel(int* __restrict__ row_start,
                                                       const int* __restrict__ blk_off,
                                                       int* __restrict__ cursor) {
    int b = blockIdx.x, t = threadIdx.x;
    int i = b * 256 + t;
    if (i >= N_NODES) return;
    int r = row_start[i] + blk_off[b];
    row_start[i] = r;
    cursor[i] = r;
}

__global__ __launch_bounds__(256) void fill_kernel(const int* __restrict__ ei,
                                                   int* __restrict__ cursor,
                                                   int* __restrict__ src_csr,
                                                   int* __restrict__ edge_pos) {
    int e = blockIdx.x * 256 + threadIdx.x;
    if (e >= N_EDGES) return;
    int s = ei[e];
    int d = ei[N_EDGES + e];
    int pos = atomicAdd(&cursor[d], 1);
    src_csr[pos] = s;
    edge_pos[e] = pos;
}

// ---------------------------------------------------------------- w_eff[h][d] = sum_c We[d, h*64+c] * att_edge[h,c]
__global__ void weff_kernel(const float* __restrict__ We, const float* __restrict__ att_edge,
                            float* __restrict__ w_eff) {
    int t = threadIdx.x;          // 64 threads
    int hh = t >> 4, d = t & 15;
    float acc = 0.f;
    #pragma unroll 8
    for (int c = 0; c < HID; ++c)
        acc += We[d * HC + hh * HID + c] * att_edge[hh * HID + c];
    w_eff[hh * 16 + d] = acc;
}

// ---------------------------------------------------------------- MFMA GEMM: C16[M,256] = f16( A16[M,K] @ Wt16^T )
// BM=64, BN=256 (wave w = head w), K = NKT*32 compile-time.
// A staged ONCE to LDS in fragment order (1 barrier); B read direct from
// global (Wt is L2-resident, 128KB shared by all blocks); C repacked via LDS
// for fully-coalesced 1KB/wave stores. Fused a_src/a_dst epilogue.
template <int NKT>
__global__ __launch_bounds__(256) void gemm16_kernel(const __half* __restrict__ A16,
                                                     const __half* __restrict__ Wt16,
                                                     __half* __restrict__ C16, int M,
                                                     const float* __restrict__ att_src,
                                                     const float* __restrict__ att_dst,
                                                     float* __restrict__ a_src,
                                                     float* __restrict__ a_dst) {
    constexpr int K = NKT * 32;
    __shared__ __align__(16) _Float16 lds[64 * 264];   // 33 KB: As (<=32KB) then Cs
    int t = threadIdx.x;
    int w = t >> 6, l = t & 63;
    int cg = l & 15, gg = l >> 4;
    int m0 = blockIdx.x * 64;

    // ---- stage A block (64 rows x K halfs) into LDS, fragment order.
    // slot f = t encodes row=(t>>6)*16+(t&15), k8=(t>>4)&3; write addr lane-contiguous.
    {
        int row = (t >> 6) * 16 + (t & 15);
        int k8 = (t >> 4) & 3;
        int rg = m0 + row;
        if (rg >= M) rg = M - 1;                       // clamp: garbage rows never stored
        const _Float16* ag = (const _Float16*)A16 + (size_t)rg * K + k8 * 8;
        f16x8 tmp[NKT];
        #pragma unroll
        for (int j = 0; j < NKT; ++j) tmp[j] = *(const f16x8*)(ag + j * 32);
        #pragma unroll
        for (int j = 0; j < NKT; ++j) *(f16x8*)&lds[(size_t)(j * 256 + t) * 8] = tmp[j];
    }
    __syncthreads();

    // ---- main loop: B from global (L2), A fragments from LDS, 16 MFMA / kt
    f32x4 acc[4][4] = {};
    const _Float16* bg = (const _Float16*)Wt16 + (size_t)(w * 64 + cg) * K + gg * 8;
    #pragma unroll 2
    for (int kt = 0; kt < NKT; ++kt) {
        f16x8 bf[4], af[4];
        #pragma unroll
        for (int ni = 0; ni < 4; ++ni)
            bf[ni] = *(const f16x8*)(bg + (size_t)(ni * 16) * K + kt * 32);
        #pragma unroll
        for (int mi = 0; mi < 4; ++mi)
            af[mi] = *(const f16x8*)&lds[(size_t)(kt * 256 + mi * 64 + l) * 8];
        #pragma unroll
        for (int mi = 0; mi < 4; ++mi)
            #pragma unroll
            for (int ni = 0; ni < 4; ++ni)
                acc[mi][ni] = __builtin_amdgcn_mfma_f32_16x16x32_f16(af[mi], bf[ni], acc[mi][ni], 0, 0, 0);
    }

    // ---- fused attdot epilogue (f32 acc); C/D: col=w*64+ni*16+cg, row=mi*16+gg*4+reg
    {
        float avs[4], avd[4];
        #pragma unroll
        for (int ni = 0; ni < 4; ++ni) {
            avs[ni] = att_src[w * 64 + ni * 16 + cg];
            avd[ni] = att_dst[w * 64 + ni * 16 + cg];
        }
        #pragma unroll
        for (int mi = 0; mi < 4; ++mi)
            #pragma unroll
            for (int reg = 0; reg < 4; ++reg) {
                float ps = acc[mi][0][reg] * avs[0] + acc[mi][1][reg] * avs[1]
                         + acc[mi][2][reg] * avs[2] + acc[mi][3][reg] * avs[3];
                float pd = acc[mi][0][reg] * avd[0] + acc[mi][1][reg] * avd[1]
                         + acc[mi][2][reg] * avd[2] + acc[mi][3][reg] * avd[3];
                #pragma unroll
                for (int o = 1; o < 16; o <<= 1) {
                    ps += __shfl_xor(ps, o, 64);
                    pd += __shfl_xor(pd, o, 64);
                }
                int m = m0 + mi * 16 + gg * 4 + reg;
                if (cg == 0 && m < M) {
                    a_src[(size_t)m * 4 + w] = ps;
                    a_dst[(size_t)m * 4 + w] = pd;
                }
            }
    }

    // ---- C repack: acc -> LDS f16 tile (stride 264, 2-way banks max) -> coalesced store
    __syncthreads();   // all waves done reading As
    #pragma unroll
    for (int mi = 0; mi < 4; ++mi)
        #pragma unroll
        for (int ni = 0; ni < 4; ++ni)
            #pragma unroll
            for (int reg = 0; reg < 4; ++reg) {
                int row = mi * 16 + gg * 4 + reg;
                int col = w * 64 + ni * 16 + cg;
                lds[row * 264 + col] = (_Float16)acc[mi][ni][reg];
            }
    __syncthreads();
    #pragma unroll
    for (int i = 0; i < 8; ++i) {
        int g = i * 256 + t;
        int row = g >> 5, cw = g & 31;
        int m = m0 + row;
        if (m < M) {
            f16x8 v = *(const f16x8*)&lds[row * 264 + cw * 8];
            *(f16x8*)((_Float16*)C16 + (size_t)m * HC + cw * 8) = v;
        }
    }
}

// ---------------------------------------------------------------- per-edge raw attention logits -> CSR order
__global__ __launch_bounds__(256) void alpha_kernel(const int* __restrict__ ei,
                                                    const float* __restrict__ edge_attr,
                                                    const float* __restrict__ w_eff,
                                                    const float* __restrict__ a_src,
                                                    const float* __restrict__ a_dst,
                                                    const int* __restrict__ edge_pos,
                                                    float4* __restrict__ alpha_csr) {
    __shared__ float wsh[64];
    int t = threadIdx.x;
    if (t < 64) wsh[t] = w_eff[t];
    __syncthreads();
    int e = blockIdx.x * 256 + t;
    if (e >= N_EDGES) return;
    int s = ei[e], d = ei[N_EDGES + e];
    const float* ea = edge_attr + (size_t)e * EDGE_DIM;
    float x[16];
    #pragma unroll
    for (int i = 0; i < 16; i += 4) {
        float4 v = *(const float4*)(ea + i);
        x[i] = v.x; x[i + 1] = v.y; x[i + 2] = v.z; x[i + 3] = v.w;
    }
    float4 as = *(const float4*)(a_src + (size_t)s * 4);
    float4 ad = *(const float4*)(a_dst + (size_t)d * 4);
    float asv[4] = {as.x, as.y, as.z, as.w};
    float adv[4] = {ad.x, ad.y, ad.z, ad.w};
    float al[4];
    #pragma unroll
    for (int hh = 0; hh < 4; ++hh) {
        float acc = 0.f;
        #pragma unroll
        for (int i = 0; i < 16; ++i) acc += x[i] * wsh[hh * 16 + i];
        float v = asv[hh] + adv[hh] + acc;
        al[hh] = v > 0.f ? v : NEG_SLOPE * v;   // leaky_relu
    }
    alpha_csr[edge_pos[e]] = make_float4(al[0], al[1], al[2], al[3]);
}

// ---------------------------------------------------------------- aggregate: wave per node, softmax + fp16 gather, fp16 out
__global__ __launch_bounds__(256) void aggregate_kernel(const int* __restrict__ src_csr,
                                                        const float4* __restrict__ alpha_csr,
                                                        const int* __restrict__ row_start,
                                                        const int* __restrict__ counts,
                                                        const __half* __restrict__ h16,
                                                        const float* __restrict__ bias,
                                                        __half* __restrict__ out16) {
    int wid = threadIdx.x >> 6, lane = threadIdx.x & 63;
    int n = blockIdx.x * 4 + wid;
    if (n >= N_NODES) return;
    int start = row_start[n];
    int deg = counts[n];
    const float4* ap = alpha_csr + start;
    const int* sp = src_csr + start;

    float m0 = -INFINITY, m1 = -INFINITY, m2 = -INFINITY, m3 = -INFINITY;
    for (int i = lane; i < deg; i += 64) {
        float4 a = ap[i];
        m0 = fmaxf(m0, a.x); m1 = fmaxf(m1, a.y);
        m2 = fmaxf(m2, a.z); m3 = fmaxf(m3, a.w);
    }
    #pragma unroll
    for (int o = 32; o > 0; o >>= 1) {
        m0 = fmaxf(m0, __shfl_xor(m0, o, 64));
        m1 = fmaxf(m1, __shfl_xor(m1, o, 64));
        m2 = fmaxf(m2, __shfl_xor(m2, o, 64));
        m3 = fmaxf(m3, __shfl_xor(m3, o, 64));
    }
    bool lo = (lane < 32);
    float mA = lo ? m0 : m1;
    float mB = lo ? m2 : m3;

    float aAx = 0.f, aAy = 0.f, aBx = 0.f, aBy = 0.f;
    float dA = 0.f, dB = 0.f;
    int s_next = (deg > 0) ? sp[0] : 0;
    #pragma unroll 2
    for (int i = 0; i < deg; ++i) {
        int s = s_next;
        if (i + 1 < deg) s_next = sp[i + 1];
        float4 a = ap[i];
        float eA = __expf((lo ? a.x : a.y) - mA);
        float eB = __expf((lo ? a.z : a.w) - mB);
        dA += eA; dB += eB;
        const __half2* hr = (const __half2*)(h16 + (size_t)s * HC);
        __half2 vA = hr[lane];
        __half2 vB = hr[64 + lane];
        float2 fA = __half22float2(vA);
        float2 fB = __half22float2(vB);
        aAx += eA * fA.x; aAy += eA * fA.y;
        aBx += eB * fB.x; aBy += eB * fB.y;
    }
    float2 b01 = *(const float2*)(bias + 2 * lane);
    float2 b23 = *(const float2*)(bias + 128 + 2 * lane);
    float invA = 1.f / (dA + EPSF);
    float invB = 1.f / (dB + EPSF);
    float r0 = fmaxf(aAx * invA + b01.x, 0.f);
    float r1 = fmaxf(aAy * invA + b01.y, 0.f);
    float r2 = fmaxf(aBx * invB + b23.x, 0.f);
    float r3 = fmaxf(aBy * invB + b23.y, 0.f);
    __half* o = out16 + (size_t)n * HC;
    *(__half2*)(o + 2 * lane)       = __floats2half2_rn(r0, r1);
    *(__half2*)(o + 128 + 2 * lane) = __floats2half2_rn(r2, r3);
}

// ---------------------------------------------------------------- pooling (batch is sorted), fp16 input
#define NPB 100
__global__ __launch_bounds__(256) void pool_kernel(const __half* __restrict__ h,
                                                   const int* __restrict__ batch,
                                                   float* __restrict__ pooled,
                                                   int* __restrict__ gcounts) {
    int t = threadIdx.x;
    int n0 = blockIdx.x * NPB;
    int n1 = n0 + NPB;
    if (n1 > N_NODES) n1 = N_NODES;
    if (n0 >= N_NODES) return;
    int cur = batch[n0];
    float acc = 0.f;
    int cnt = 0;
    for (int n = n0; n < n1; ++n) {
        int g = batch[n];
        if (g != cur) {
            atomicAdd(&pooled[cur * HC + t], acc);
            if (t == 0) atomicAdd(&gcounts[cur], cnt);
            acc = 0.f; cnt = 0; cur = g;
        }
        acc += __half2float(h[(size_t)n * HC + t]);
        cnt++;
    }
    atomicAdd(&pooled[cur * HC + t], acc);
    if (t == 0) atomicAdd(&gcounts[cur], cnt);
}

__global__ __launch_bounds__(256) void finalize_kernel(const float* __restrict__ pooled,
                                                       const int* __restrict__ gcounts,
                                                       float* __restrict__ out) {
    int g = blockIdx.x, t = threadIdx.x;
    float c = (float)(gcounts[g] > 1 ? gcounts[g] : 1);
    out[g * HC + t] = tanhf(pooled[g * HC + t] / c);
}

// ---------------------------------------------------------------- launch
extern "C" void kernel_launch(void* const* d_in, const int* in_sizes, int n_in,
                              void* d_out, int out_size, void* d_ws, size_t ws_size,
                              hipStream_t stream) {
    const float* x         = (const float*)d_in[0];
    const int*   ei        = (const int*)d_in[1];
    const float* edge_attr = (const float*)d_in[2];
    const int*   batch     = (const int*)d_in[3];
    const float* Wl[3]  = {(const float*)d_in[4],  (const float*)d_in[10], (const float*)d_in[16]};
    const float* Wel[3] = {(const float*)d_in[5],  (const float*)d_in[11], (const float*)d_in[17]};
    const float* asl[3] = {(const float*)d_in[6],  (const float*)d_in[12], (const float*)d_in[18]};
    const float* adl[3] = {(const float*)d_in[7],  (const float*)d_in[13], (const float*)d_in[19]};
    const float* ael[3] = {(const float*)d_in[8],  (const float*)d_in[14], (const float*)d_in[20]};
    const float* bl[3]  = {(const float*)d_in[9],  (const float*)d_in[15], (const float*)d_in[21]};
    float* out = (float*)d_out;

    // workspace carve (256B aligned)
    char* p = (char*)d_ws;
    auto alloc = [&](size_t bytes) -> void* {
        void* r = (void*)p;
        p += (bytes + 255) & ~(size_t)255;
        return r;
    };
    __half* x16       = (__half*)alloc((size_t)N_NODES * OBS * 2);
    __half* hA16      = (__half*)alloc((size_t)N_NODES * HC * 2);
    __half* hB16      = (__half*)alloc((size_t)N_NODES * HC * 2);
    __half* wt0       = (__half*)alloc((size_t)HC * OBS * 2);
    __half* wt1       = (__half*)alloc((size_t)HC * HC * 2);
    __half* wt2       = (__half*)alloc((size_t)HC * HC * 2);
    float* a_src      = (float*)alloc((size_t)N_NODES * 4 * 4);
    float* a_dst      = (float*)alloc((size_t)N_NODES * 4 * 4);
    float4* alpha_csr = (float4*)alloc((size_t)N_EDGES * 16);
    int* counts       = (int*)alloc((size_t)N_NODES * 4);
    int* row_start    = (int*)alloc((size_t)N_NODES * 4);
    int* cursor       = (int*)alloc((size_t)N_NODES * 4);
    int* src_csr      = (int*)alloc((size_t)N_EDGES * 4);
    int* edge_pos     = (int*)alloc((size_t)N_EDGES * 4);
    float* w_eff      = (float*)alloc(64 * 4);
    float* pooled     = (float*)alloc((size_t)N_GRAPHS * HC * 4);
    int* gcounts      = (int*)alloc((size_t)N_GRAPHS * 4);
    int* blk_tot      = (int*)alloc((size_t)N_SCAN_BLOCKS * 4);
    int* blk_off      = (int*)alloc((size_t)N_SCAN_BLOCKS * 4);

    // zero scratch that accumulates
    zero_kernel<<<(N_NODES + 255) / 256, 256, 0, stream>>>((unsigned int*)counts, N_NODES);
    zero_kernel<<<(N_GRAPHS * HC + 255) / 256, 256, 0, stream>>>((unsigned int*)pooled, N_GRAPHS * HC);
    zero_kernel<<<1, 256, 0, stream>>>((unsigned int*)gcounts, N_GRAPHS);

    // input/weight conversions
    cvt_kernel<<<(N_NODES * OBS / 4 + 255) / 256, 256, 0, stream>>>(x, x16, N_NODES * OBS);
    wt_kernel<<<OBS, 256, 0, stream>>>(Wl[0], wt0, OBS);
    wt_kernel<<<HC, 256, 0, stream>>>(Wl[1], wt1, HC);
    wt_kernel<<<HC, 256, 0, stream>>>(Wl[2], wt2, HC);

    // CSR build over dst (parallel two-level scan)
    count_kernel<<<N_EDGES / 256, 256, 0, stream>>>(ei, counts);
    scan_local_kernel<<<N_SCAN_BLOCKS, 256, 0, stream>>>(counts, row_start, blk_tot);
    scan_offsets_kernel<<<1, 128, 0, stream>>>(blk_tot, blk_off);
    scan_add_kernel<<<N_SCAN_BLOCKS, 256, 0, stream>>>(row_start, blk_off, cursor);
    fill_kernel<<<N_EDGES / 256, 256, 0, stream>>>(ei, cursor, src_csr, edge_pos);

    const int ngrid = (N_NODES + 63) / 64;
    const __half* wtl[3] = {wt0, wt1, wt2};
    const __half* cur_in = x16;
    for (int l = 0; l < 3; ++l) {
        if (l == 0)
            gemm16_kernel<2><<<ngrid, 256, 0, stream>>>(cur_in, wtl[l], hA16, N_NODES,
                                                        asl[l], adl[l], a_src, a_dst);
        else
            gemm16_kernel<8><<<ngrid, 256, 0, stream>>>(cur_in, wtl[l], hA16, N_NODES,
                                                        asl[l], adl[l], a_src, a_dst);
        weff_kernel<<<1, 64, 0, stream>>>(Wel[l], ael[l], w_eff);
        alpha_kernel<<<N_EDGES / 256, 256, 0, stream>>>(ei, edge_attr, w_eff, a_src, a_dst,
                                                        edge_pos, alpha_csr);
        aggregate_kernel<<<(N_NODES + 3) / 4, 256, 0, stream>>>(src_csr, alpha_csr, row_start,
                                                                counts, hA16, bl[l], hB16);
        cur_in = hB16;
    }

    // global mean pool + tanh
    pool_kernel<<<(N_NODES + NPB - 1) / NPB, 256, 0, stream>>>(hB16, batch, pooled, gcounts);
    finalize_kernel<<<N_GRAPHS, 256, 0, stream>>>(pooled, gcounts, out);
}

// Round 8
// 250.401 us; speedup vs baseline: 1.2391x; 1.1180x over previous
//
#include <hip/hip_runtime.h>
#include <hip/hip_bf16.h>
#include <hip/hip_fp16.h>
#include <math.h>

#define N_NODES 20000
#define N_EDGES 320000
#define N_GRAPHS 64
#define OBS 64
#define EDGE_DIM 16
#define HEADS 4
#define HID 64
#define HC 256            // HEADS*HID
#define NEG_SLOPE 0.2f
#define EPSF 1e-16f
#define N_SCAN_BLOCKS ((N_NODES + 255) / 256)   // 79
#define CVT_BLOCKS (N_NODES * OBS / 4 / 256)    // 1250

typedef _Float16 f16x8 __attribute__((ext_vector_type(8)));
typedef float f32x4 __attribute__((ext_vector_type(4)));

// ---------------------------------------------------------------- fused zero (counts, pooled, gcounts)
__global__ __launch_bounds__(256) void zero3_kernel(int* __restrict__ counts,
                                                    float* __restrict__ pooled,
                                                    int* __restrict__ gcounts) {
    int i = blockIdx.x * 256 + threadIdx.x;
    if (i < N_NODES) counts[i] = 0;
    if (i < N_GRAPHS * HC) pooled[i] = 0.f;
    if (i < N_GRAPHS) gcounts[i] = 0;
}

// ---------------------------------------------------------------- fused x->f16 convert + 3x weight transpose
__global__ __launch_bounds__(256) void cvtwt_kernel(const float* __restrict__ x, __half* __restrict__ x16,
                                                    const float* __restrict__ W0, const float* __restrict__ W1,
                                                    const float* __restrict__ W2,
                                                    __half* __restrict__ wt0, __half* __restrict__ wt1,
                                                    __half* __restrict__ wt2) {
    int b = blockIdx.x, t = threadIdx.x;
    if (b < CVT_BLOCKS) {
        int i = (b * 256 + t) * 4;
        float4 v = *(const float4*)(x + i);
        *(__half2*)(x16 + i)     = __floats2half2_rn(v.x, v.y);
        *(__half2*)(x16 + i + 2) = __floats2half2_rn(v.z, v.w);
    } else if (b < CVT_BLOCKS + OBS) {
        int k = b - CVT_BLOCKS;
        wt0[(size_t)t * OBS + k] = __float2half(W0[(size_t)k * HC + t]);
    } else if (b < CVT_BLOCKS + OBS + HC) {
        int k = b - CVT_BLOCKS - OBS;
        wt1[(size_t)t * HC + k] = __float2half(W1[(size_t)k * HC + t]);
    } else {
        int k = b - CVT_BLOCKS - OBS - HC;
        wt2[(size_t)t * HC + k] = __float2half(W2[(size_t)k * HC + t]);
    }
}

// ---------------------------------------------------------------- CSR build
__global__ __launch_bounds__(256) void count_kernel(const int* __restrict__ ei, int* __restrict__ counts) {
    int e = blockIdx.x * 256 + threadIdx.x;
    if (e >= N_EDGES) return;
    atomicAdd(&counts[ei[N_EDGES + e]], 1);
}

__global__ __launch_bounds__(256) void scan_local_kernel(const int* __restrict__ counts,
                                                         int* __restrict__ row_start,
                                                         int* __restrict__ blk_tot) {
    int b = blockIdx.x, t = threadIdx.x;
    int i = b * 256 + t;
    int v = (i < N_NODES) ? counts[i] : 0;
    int lane = t & 63, w = t >> 6;
    int x = v;
    #pragma unroll
    for (int off = 1; off < 64; off <<= 1) {
        int y = __shfl_up(x, off, 64);
        if (lane >= off) x += y;
    }
    __shared__ int wsum[4];
    __shared__ int woff[4];
    if (lane == 63) wsum[w] = x;
    __syncthreads();
    if (t == 0) {
        int s = 0;
        #pragma unroll
        for (int k = 0; k < 4; ++k) { woff[k] = s; s += wsum[k]; }
        blk_tot[b] = s;
    }
    __syncthreads();
    if (i < N_NODES) row_start[i] = x - v + woff[w];
}

// add block offsets (each block tree-reduces the totals of blocks before it)
__global__ __launch_bounds__(256) void scan_add_kernel(int* __restrict__ row_start,
                                                       const int* __restrict__ blk_tot,
                                                       int* __restrict__ cursor) {
    __shared__ int sd[128];
    int b = blockIdx.x, t = threadIdx.x;
    if (t < 128) sd[t] = (t < b && t < N_SCAN_BLOCKS) ? blk_tot[t] : 0;
    __syncthreads();
    #pragma unroll
    for (int off = 64; off >= 1; off >>= 1) {
        if (t < off) sd[t] += sd[t + off];
        __syncthreads();
    }
    int base = sd[0];
    int i = b * 256 + t;
    if (i < N_NODES) {
        int r = row_start[i] + base;
        row_start[i] = r;
        cursor[i] = r;
    }
}

__global__ __launch_bounds__(256) void fill_kernel(const int* __restrict__ ei,
                                                   int* __restrict__ cursor,
                                                   int* __restrict__ src_csr,
                                                   int* __restrict__ edge_pos) {
    int e = blockIdx.x * 256 + threadIdx.x;
    if (e >= N_EDGES) return;
    int s = ei[e];
    int d = ei[N_EDGES + e];
    int pos = atomicAdd(&cursor[d], 1);
    src_csr[pos] = s;
    edge_pos[e] = pos;
}

// ---------------------------------------------------------------- w_eff3[l][h][d] for all 3 layers (3 blocks x 64 thr)
__global__ void weff3_kernel(const float* __restrict__ We0, const float* __restrict__ ae0,
                             const float* __restrict__ We1, const float* __restrict__ ae1,
                             const float* __restrict__ We2, const float* __restrict__ ae2,
                             float* __restrict__ w_eff3) {
    int l = blockIdx.x, t = threadIdx.x;   // 64 threads
    const float* We = (l == 0) ? We0 : (l == 1) ? We1 : We2;
    const float* ae = (l == 0) ? ae0 : (l == 1) ? ae1 : ae2;
    int hh = t >> 4, d = t & 15;
    float acc = 0.f;
    #pragma unroll 8
    for (int c = 0; c < HID; ++c)
        acc += We[d * HC + hh * HID + c] * ae[hh * HID + c];
    w_eff3[l * 64 + hh * 16 + d] = acc;
}

// ---------------------------------------------------------------- per-edge dots for ALL layers -> CSR order
// ae_csr[l*N_EDGES + pos] = float4 of per-head edge dots (layer l)
__global__ __launch_bounds__(256) void ae3_kernel(const float* __restrict__ edge_attr,
                                                  const int* __restrict__ edge_pos,
                                                  const float* __restrict__ w_eff3,
                                                  float4* __restrict__ ae_csr) {
    __shared__ float wsh[192];
    int t = threadIdx.x;
    if (t < 192) wsh[t] = w_eff3[t];
    __syncthreads();
    int e = blockIdx.x * 256 + t;
    if (e >= N_EDGES) return;
    const float* ea = edge_attr + (size_t)e * EDGE_DIM;
    float x[16];
    #pragma unroll
    for (int i = 0; i < 16; i += 4) {
        float4 v = *(const float4*)(ea + i);
        x[i] = v.x; x[i + 1] = v.y; x[i + 2] = v.z; x[i + 3] = v.w;
    }
    int pos = edge_pos[e];
    #pragma unroll
    for (int l = 0; l < 3; ++l) {
        float al[4];
        #pragma unroll
        for (int hh = 0; hh < 4; ++hh) {
            float acc = 0.f;
            #pragma unroll
            for (int i = 0; i < 16; ++i) acc += x[i] * wsh[l * 64 + hh * 16 + i];
            al[hh] = acc;
        }
        ae_csr[(size_t)l * N_EDGES + pos] = make_float4(al[0], al[1], al[2], al[3]);
    }
}

// ---------------------------------------------------------------- MFMA GEMM (unchanged from round 7, verified)
template <int NKT>
__global__ __launch_bounds__(256) void gemm16_kernel(const __half* __restrict__ A16,
                                                     const __half* __restrict__ Wt16,
                                                     __half* __restrict__ C16, int M,
                                                     const float* __restrict__ att_src,
                                                     const float* __restrict__ att_dst,
                                                     float* __restrict__ a_src,
                                                     float* __restrict__ a_dst) {
    constexpr int K = NKT * 32;
    __shared__ __align__(16) _Float16 lds[64 * 264];   // 33 KB: As (<=32KB) then Cs
    int t = threadIdx.x;
    int w = t >> 6, l = t & 63;
    int cg = l & 15, gg = l >> 4;
    int m0 = blockIdx.x * 64;

    {
        int row = (t >> 6) * 16 + (t & 15);
        int k8 = (t >> 4) & 3;
        int rg = m0 + row;
        if (rg >= M) rg = M - 1;
        const _Float16* ag = (const _Float16*)A16 + (size_t)rg * K + k8 * 8;
        f16x8 tmp[NKT];
        #pragma unroll
        for (int j = 0; j < NKT; ++j) tmp[j] = *(const f16x8*)(ag + j * 32);
        #pragma unroll
        for (int j = 0; j < NKT; ++j) *(f16x8*)&lds[(size_t)(j * 256 + t) * 8] = tmp[j];
    }
    __syncthreads();

    f32x4 acc[4][4] = {};
    const _Float16* bg = (const _Float16*)Wt16 + (size_t)(w * 64 + cg) * K + gg * 8;
    #pragma unroll 2
    for (int kt = 0; kt < NKT; ++kt) {
        f16x8 bf[4], af[4];
        #pragma unroll
        for (int ni = 0; ni < 4; ++ni)
            bf[ni] = *(const f16x8*)(bg + (size_t)(ni * 16) * K + kt * 32);
        #pragma unroll
        for (int mi = 0; mi < 4; ++mi)
            af[mi] = *(const f16x8*)&lds[(size_t)(kt * 256 + mi * 64 + l) * 8];
        #pragma unroll
        for (int mi = 0; mi < 4; ++mi)
            #pragma unroll
            for (int ni = 0; ni < 4; ++ni)
                acc[mi][ni] = __builtin_amdgcn_mfma_f32_16x16x32_f16(af[mi], bf[ni], acc[mi][ni], 0, 0, 0);
    }

    {
        float avs[4], avd[4];
        #pragma unroll
        for (int ni = 0; ni < 4; ++ni) {
            avs[ni] = att_src[w * 64 + ni * 16 + cg];
            avd[ni] = att_dst[w * 64 + ni * 16 + cg];
        }
        #pragma unroll
        for (int mi = 0; mi < 4; ++mi)
            #pragma unroll
            for (int reg = 0; reg < 4; ++reg) {
                float ps = acc[mi][0][reg] * avs[0] + acc[mi][1][reg] * avs[1]
                         + acc[mi][2][reg] * avs[2] + acc[mi][3][reg] * avs[3];
                float pd = acc[mi][0][reg] * avd[0] + acc[mi][1][reg] * avd[1]
                         + acc[mi][2][reg] * avd[2] + acc[mi][3][reg] * avd[3];
                #pragma unroll
                for (int o = 1; o < 16; o <<= 1) {
                    ps += __shfl_xor(ps, o, 64);
                    pd += __shfl_xor(pd, o, 64);
                }
                int m = m0 + mi * 16 + gg * 4 + reg;
                if (cg == 0 && m < M) {
                    a_src[(size_t)m * 4 + w] = ps;
                    a_dst[(size_t)m * 4 + w] = pd;
                }
            }
    }

    __syncthreads();
    #pragma unroll
    for (int mi = 0; mi < 4; ++mi)
        #pragma unroll
        for (int ni = 0; ni < 4; ++ni)
            #pragma unroll
            for (int reg = 0; reg < 4; ++reg) {
                int row = mi * 16 + gg * 4 + reg;
                int col = w * 64 + ni * 16 + cg;
                lds[row * 264 + col] = (_Float16)acc[mi][ni][reg];
            }
    __syncthreads();
    #pragma unroll
    for (int i = 0; i < 8; ++i) {
        int g = i * 256 + t;
        int row = g >> 5, cw = g & 31;
        int m = m0 + row;
        if (m < M) {
            f16x8 v = *(const f16x8*)&lds[row * 264 + cw * 8];
            *(f16x8*)((_Float16*)C16 + (size_t)m * HC + cw * 8) = v;
        }
    }
}

// ---------------------------------------------------------------- aggregate2: fused logits + softmax + fp16 gather
// wave per node; pass A computes alpha=lrelu(ae+asrc+adst), caches in LDS (<=64 edges), tracks max;
// pass B: exp + weighted gather of h16 rows. Lane l: heads 0/1 (lo/hi half-wave) chans 2l, heads 2/3 chans 128+2l.
__global__ __launch_bounds__(256) void aggregate2_kernel(const int* __restrict__ src_csr,
                                                         const float4* __restrict__ ae_csr,
                                                         const int* __restrict__ row_start,
                                                         const int* __restrict__ counts,
                                                         const float* __restrict__ a_src,
                                                         const float* __restrict__ a_dst,
                                                         const __half* __restrict__ h16,
                                                         const float* __restrict__ bias,
                                                         __half* __restrict__ out16) {
    __shared__ float4 alds[4][64];
    int wid = threadIdx.x >> 6, lane = threadIdx.x & 63;
    int n = blockIdx.x * 4 + wid;                 // grid == 5000 exactly, n < 20000 always
    int start = row_start[n];
    int deg = counts[n];
    const float4* ae = ae_csr + start;
    const int* sp = src_csr + start;
    float4 ad = *(const float4*)(a_dst + (size_t)n * 4);

    // pass A: compute logits, cache, track per-head max
    float m0 = -INFINITY, m1 = -INFINITY, m2 = -INFINITY, m3 = -INFINITY;
    for (int i = lane; i < deg; i += 64) {
        float4 a = ae[i];
        int s = sp[i];
        float4 as = *(const float4*)(a_src + (size_t)s * 4);
        float v0 = a.x + as.x + ad.x; v0 = v0 > 0.f ? v0 : NEG_SLOPE * v0;
        float v1 = a.y + as.y + ad.y; v1 = v1 > 0.f ? v1 : NEG_SLOPE * v1;
        float v2 = a.z + as.z + ad.z; v2 = v2 > 0.f ? v2 : NEG_SLOPE * v2;
        float v3 = a.w + as.w + ad.w; v3 = v3 > 0.f ? v3 : NEG_SLOPE * v3;
        if (i < 64) alds[wid][i] = make_float4(v0, v1, v2, v3);
        m0 = fmaxf(m0, v0); m1 = fmaxf(m1, v1);
        m2 = fmaxf(m2, v2); m3 = fmaxf(m3, v3);
    }
    #pragma unroll
    for (int o = 32; o > 0; o >>= 1) {
        m0 = fmaxf(m0, __shfl_xor(m0, o, 64));
        m1 = fmaxf(m1, __shfl_xor(m1, o, 64));
        m2 = fmaxf(m2, __shfl_xor(m2, o, 64));
        m3 = fmaxf(m3, __shfl_xor(m3, o, 64));
    }
    __syncthreads();   // LDS alpha cache visible to all lanes

    bool lo = (lane < 32);
    float mA = lo ? m0 : m1;
    float mB = lo ? m2 : m3;

    // pass B: serial over edges, exp + fp16 row gather
    float aAx = 0.f, aAy = 0.f, aBx = 0.f, aBy = 0.f;
    float dA = 0.f, dB = 0.f;
    int s_next = (deg > 0) ? sp[0] : 0;
    #pragma unroll 2
    for (int i = 0; i < deg; ++i) {
        int s = s_next;
        if (i + 1 < deg) s_next = sp[i + 1];
        float4 al;
        if (i < 64) {
            al = alds[wid][i];
        } else {   // rare fallback: recompute
            float4 a = ae[i];
            float4 as = *(const float4*)(a_src + (size_t)s * 4);
            al.x = a.x + as.x + ad.x; al.x = al.x > 0.f ? al.x : NEG_SLOPE * al.x;
            al.y = a.y + as.y + ad.y; al.y = al.y > 0.f ? al.y : NEG_SLOPE * al.y;
            al.z = a.z + as.z + ad.z; al.z = al.z > 0.f ? al.z : NEG_SLOPE * al.z;
            al.w = a.w + as.w + ad.w; al.w = al.w > 0.f ? al.w : NEG_SLOPE * al.w;
        }
        float eA = __expf((lo ? al.x : al.y) - mA);
        float eB = __expf((lo ? al.z : al.w) - mB);
        dA += eA; dB += eB;
        const __half2* hr = (const __half2*)(h16 + (size_t)s * HC);
        __half2 vA = hr[lane];
        __half2 vB = hr[64 + lane];
        float2 fA = __half22float2(vA);
        float2 fB = __half22float2(vB);
        aAx += eA * fA.x; aAy += eA * fA.y;
        aBx += eB * fB.x; aBy += eB * fB.y;
    }
    float2 b01 = *(const float2*)(bias + 2 * lane);
    float2 b23 = *(const float2*)(bias + 128 + 2 * lane);
    float invA = 1.f / (dA + EPSF);
    float invB = 1.f / (dB + EPSF);
    float r0 = fmaxf(aAx * invA + b01.x, 0.f);
    float r1 = fmaxf(aAy * invA + b01.y, 0.f);
    float r2 = fmaxf(aBx * invB + b23.x, 0.f);
    float r3 = fmaxf(aBy * invB + b23.y, 0.f);
    __half* o = out16 + (size_t)n * HC;
    *(__half2*)(o + 2 * lane)       = __floats2half2_rn(r0, r1);
    *(__half2*)(o + 128 + 2 * lane) = __floats2half2_rn(r2, r3);
}

// ---------------------------------------------------------------- pooling (batch is sorted), fp16 input
#define NPB 100
__global__ __launch_bounds__(256) void pool_kernel(const __half* __restrict__ h,
                                                   const int* __restrict__ batch,
                                                   float* __restrict__ pooled,
                                                   int* __restrict__ gcounts) {
    int t = threadIdx.x;
    int n0 = blockIdx.x * NPB;
    int n1 = n0 + NPB;
    if (n1 > N_NODES) n1 = N_NODES;
    if (n0 >= N_NODES) return;
    int cur = batch[n0];
    float acc = 0.f;
    int cnt = 0;
    for (int n = n0; n < n1; ++n) {
        int g = batch[n];
        if (g != cur) {
            atomicAdd(&pooled[cur * HC + t], acc);
            if (t == 0) atomicAdd(&gcounts[cur], cnt);
            acc = 0.f; cnt = 0; cur = g;
        }
        acc += __half2float(h[(size_t)n * HC + t]);
        cnt++;
    }
    atomicAdd(&pooled[cur * HC + t], acc);
    if (t == 0) atomicAdd(&gcounts[cur], cnt);
}

__global__ __launch_bounds__(256) void finalize_kernel(const float* __restrict__ pooled,
                                                       const int* __restrict__ gcounts,
                                                       float* __restrict__ out) {
    int g = blockIdx.x, t = threadIdx.x;
    float c = (float)(gcounts[g] > 1 ? gcounts[g] : 1);
    out[g * HC + t] = tanhf(pooled[g * HC + t] / c);
}

// ---------------------------------------------------------------- launch
extern "C" void kernel_launch(void* const* d_in, const int* in_sizes, int n_in,
                              void* d_out, int out_size, void* d_ws, size_t ws_size,
                              hipStream_t stream) {
    const float* x         = (const float*)d_in[0];
    const int*   ei        = (const int*)d_in[1];
    const float* edge_attr = (const float*)d_in[2];
    const int*   batch     = (const int*)d_in[3];
    const float* Wl[3]  = {(const float*)d_in[4],  (const float*)d_in[10], (const float*)d_in[16]};
    const float* Wel[3] = {(const float*)d_in[5],  (const float*)d_in[11], (const float*)d_in[17]};
    const float* asl[3] = {(const float*)d_in[6],  (const float*)d_in[12], (const float*)d_in[18]};
    const float* adl[3] = {(const float*)d_in[7],  (const float*)d_in[13], (const float*)d_in[19]};
    const float* ael[3] = {(const float*)d_in[8],  (const float*)d_in[14], (const float*)d_in[20]};
    const float* bl[3]  = {(const float*)d_in[9],  (const float*)d_in[15], (const float*)d_in[21]};
    float* out = (float*)d_out;

    // workspace carve (256B aligned)
    char* p = (char*)d_ws;
    auto alloc = [&](size_t bytes) -> void* {
        void* r = (void*)p;
        p += (bytes + 255) & ~(size_t)255;
        return r;
    };
    __half* x16       = (__half*)alloc((size_t)N_NODES * OBS * 2);
    __half* hA16      = (__half*)alloc((size_t)N_NODES * HC * 2);
    __half* hB16      = (__half*)alloc((size_t)N_NODES * HC * 2);
    __half* wt0       = (__half*)alloc((size_t)HC * OBS * 2);
    __half* wt1       = (__half*)alloc((size_t)HC * HC * 2);
    __half* wt2       = (__half*)alloc((size_t)HC * HC * 2);
    float* a_src      = (float*)alloc((size_t)N_NODES * 4 * 4);
    float* a_dst      = (float*)alloc((size_t)N_NODES * 4 * 4);
    float4* ae_csr    = (float4*)alloc((size_t)3 * N_EDGES * 16);
    int* counts       = (int*)alloc((size_t)N_NODES * 4);
    int* row_start    = (int*)alloc((size_t)N_NODES * 4);
    int* cursor       = (int*)alloc((size_t)N_NODES * 4);
    int* src_csr      = (int*)alloc((size_t)N_EDGES * 4);
    int* edge_pos     = (int*)alloc((size_t)N_EDGES * 4);
    float* w_eff3     = (float*)alloc(192 * 4);
    float* pooled     = (float*)alloc((size_t)N_GRAPHS * HC * 4);
    int* gcounts      = (int*)alloc((size_t)N_GRAPHS * 4);
    int* blk_tot      = (int*)alloc((size_t)N_SCAN_BLOCKS * 4);

    // fused zero + conversions + weff (no inter-deps)
    zero3_kernel<<<N_SCAN_BLOCKS, 256, 0, stream>>>(counts, pooled, gcounts);
    cvtwt_kernel<<<CVT_BLOCKS + OBS + HC + HC, 256, 0, stream>>>(x, x16, Wl[0], Wl[1], Wl[2],
                                                                 wt0, wt1, wt2);
    weff3_kernel<<<3, 64, 0, stream>>>(Wel[0], ael[0], Wel[1], ael[1], Wel[2], ael[2], w_eff3);

    // CSR build over dst
    count_kernel<<<N_EDGES / 256, 256, 0, stream>>>(ei, counts);
    scan_local_kernel<<<N_SCAN_BLOCKS, 256, 0, stream>>>(counts, row_start, blk_tot);
    scan_add_kernel<<<N_SCAN_BLOCKS, 256, 0, stream>>>(row_start, blk_tot, cursor);
    fill_kernel<<<N_EDGES / 256, 256, 0, stream>>>(ei, cursor, src_csr, edge_pos);

    // all-layer edge dots in CSR order
    ae3_kernel<<<N_EDGES / 256, 256, 0, stream>>>(edge_attr, edge_pos, w_eff3, ae_csr);

    const int ngrid = (N_NODES + 63) / 64;
    const __half* wtl[3] = {wt0, wt1, wt2};
    const __half* cur_in = x16;
    for (int l = 0; l < 3; ++l) {
        if (l == 0)
            gemm16_kernel<2><<<ngrid, 256, 0, stream>>>(cur_in, wtl[l], hA16, N_NODES,
                                                        asl[l], adl[l], a_src, a_dst);
        else
            gemm16_kernel<8><<<ngrid, 256, 0, stream>>>(cur_in, wtl[l], hA16, N_NODES,
                                                        asl[l], adl[l], a_src, a_dst);
        aggregate2_kernel<<<N_NODES / 4, 256, 0, stream>>>(src_csr, ae_csr + (size_t)l * N_EDGES,
                                                           row_start, counts, a_src, a_dst,
                                                           hA16, bl[l], hB16);
        cur_in = hB16;
    }

    // global mean pool + tanh
    pool_kernel<<<(N_NODES + NPB - 1) / NPB, 256, 0, stream>>>(hB16, batch, pooled, gcounts);
    finalize_kernel<<<N_GRAPHS, 256, 0, stream>>>(pooled, gcounts, out);
}

// Round 9
// 244.512 us; speedup vs baseline: 1.2690x; 1.0241x over previous
//
#include <hip/hip_runtime.h>
#include <hip/hip_bf16.h>
#include <hip/hip_fp16.h>
#include <math.h>

#define N_NODES 20000
#define N_EDGES 320000
#define N_GRAPHS 64
#define OBS 64
#define EDGE_DIM 16
#define HEADS 4
#define HID 64
#define HC 256            // HEADS*HID
#define NEG_SLOPE 0.2f
#define EPSF 1e-16f
#define N_SCAN_BLOCKS ((N_NODES + 255) / 256)   // 79
#define CVT_BLOCKS (N_NODES * OBS / 4 / 256)    // 1250
#define CAP 64            // per-node LDS weight cache (edges)

typedef _Float16 f16x8 __attribute__((ext_vector_type(8)));
typedef float f32x4 __attribute__((ext_vector_type(4)));

// ---------------------------------------------------------------- fused zero (counts, pooled, gcounts)
__global__ __launch_bounds__(256) void zero3_kernel(int* __restrict__ counts,
                                                    float* __restrict__ pooled,
                                                    int* __restrict__ gcounts) {
    int i = blockIdx.x * 256 + threadIdx.x;
    if (i < N_NODES) counts[i] = 0;
    if (i < N_GRAPHS * HC) pooled[i] = 0.f;
    if (i < N_GRAPHS) gcounts[i] = 0;
}

// ---------------------------------------------------------------- fused x->f16 convert + 3x weight transpose
__global__ __launch_bounds__(256) void cvtwt_kernel(const float* __restrict__ x, __half* __restrict__ x16,
                                                    const float* __restrict__ W0, const float* __restrict__ W1,
                                                    const float* __restrict__ W2,
                                                    __half* __restrict__ wt0, __half* __restrict__ wt1,
                                                    __half* __restrict__ wt2) {
    int b = blockIdx.x, t = threadIdx.x;
    if (b < CVT_BLOCKS) {
        int i = (b * 256 + t) * 4;
        float4 v = *(const float4*)(x + i);
        *(__half2*)(x16 + i)     = __floats2half2_rn(v.x, v.y);
        *(__half2*)(x16 + i + 2) = __floats2half2_rn(v.z, v.w);
    } else if (b < CVT_BLOCKS + OBS) {
        int k = b - CVT_BLOCKS;
        wt0[(size_t)t * OBS + k] = __float2half(W0[(size_t)k * HC + t]);
    } else if (b < CVT_BLOCKS + OBS + HC) {
        int k = b - CVT_BLOCKS - OBS;
        wt1[(size_t)t * HC + k] = __float2half(W1[(size_t)k * HC + t]);
    } else {
        int k = b - CVT_BLOCKS - OBS - HC;
        wt2[(size_t)t * HC + k] = __float2half(W2[(size_t)k * HC + t]);
    }
}

// ---------------------------------------------------------------- CSR build
__global__ __launch_bounds__(256) void count_kernel(const int* __restrict__ ei, int* __restrict__ counts) {
    int e = blockIdx.x * 256 + threadIdx.x;
    if (e >= N_EDGES) return;
    atomicAdd(&counts[ei[N_EDGES + e]], 1);
}

__global__ __launch_bounds__(256) void scan_local_kernel(const int* __restrict__ counts,
                                                         int* __restrict__ row_start,
                                                         int* __restrict__ blk_tot) {
    int b = blockIdx.x, t = threadIdx.x;
    int i = b * 256 + t;
    int v = (i < N_NODES) ? counts[i] : 0;
    int lane = t & 63, w = t >> 6;
    int x = v;
    #pragma unroll
    for (int off = 1; off < 64; off <<= 1) {
        int y = __shfl_up(x, off, 64);
        if (lane >= off) x += y;
    }
    __shared__ int wsum[4];
    __shared__ int woff[4];
    if (lane == 63) wsum[w] = x;
    __syncthreads();
    if (t == 0) {
        int s = 0;
        #pragma unroll
        for (int k = 0; k < 4; ++k) { woff[k] = s; s += wsum[k]; }
        blk_tot[b] = s;
    }
    __syncthreads();
    if (i < N_NODES) row_start[i] = x - v + woff[w];
}

__global__ __launch_bounds__(256) void scan_add_kernel(int* __restrict__ row_start,
                                                       const int* __restrict__ blk_tot,
                                                       int* __restrict__ cursor) {
    __shared__ int sd[128];
    int b = blockIdx.x, t = threadIdx.x;
    if (t < 128) sd[t] = (t < b && t < N_SCAN_BLOCKS) ? blk_tot[t] : 0;
    __syncthreads();
    #pragma unroll
    for (int off = 64; off >= 1; off >>= 1) {
        if (t < off) sd[t] += sd[t + off];
        __syncthreads();
    }
    int base = sd[0];
    int i = b * 256 + t;
    if (i < N_NODES) {
        int r = row_start[i] + base;
        row_start[i] = r;
        cursor[i] = r;
    }
}

__global__ __launch_bounds__(256) void fill_kernel(const int* __restrict__ ei,
                                                   int* __restrict__ cursor,
                                                   int* __restrict__ src_csr,
                                                   int* __restrict__ edge_pos) {
    int e = blockIdx.x * 256 + threadIdx.x;
    if (e >= N_EDGES) return;
    int s = ei[e];
    int d = ei[N_EDGES + e];
    int pos = atomicAdd(&cursor[d], 1);
    src_csr[pos] = s;
    edge_pos[e] = pos;
}

// ---------------------------------------------------------------- w_eff3[l][h][d] for all 3 layers
__global__ void weff3_kernel(const float* __restrict__ We0, const float* __restrict__ ae0,
                             const float* __restrict__ We1, const float* __restrict__ ae1,
                             const float* __restrict__ We2, const float* __restrict__ ae2,
                             float* __restrict__ w_eff3) {
    int l = blockIdx.x, t = threadIdx.x;   // 64 threads
    const float* We = (l == 0) ? We0 : (l == 1) ? We1 : We2;
    const float* ae = (l == 0) ? ae0 : (l == 1) ? ae1 : ae2;
    int hh = t >> 4, d = t & 15;
    float acc = 0.f;
    #pragma unroll 8
    for (int c = 0; c < HID; ++c)
        acc += We[d * HC + hh * HID + c] * ae[hh * HID + c];
    w_eff3[l * 64 + hh * 16 + d] = acc;
}

// ---------------------------------------------------------------- per-edge dots for ALL layers -> CSR order
__global__ __launch_bounds__(256) void ae3_kernel(const float* __restrict__ edge_attr,
                                                  const int* __restrict__ edge_pos,
                                                  const float* __restrict__ w_eff3,
                                                  float4* __restrict__ ae_csr) {
    __shared__ float wsh[192];
    int t = threadIdx.x;
    if (t < 192) wsh[t] = w_eff3[t];
    __syncthreads();
    int e = blockIdx.x * 256 + t;
    if (e >= N_EDGES) return;
    const float* ea = edge_attr + (size_t)e * EDGE_DIM;
    float x[16];
    #pragma unroll
    for (int i = 0; i < 16; i += 4) {
        float4 v = *(const float4*)(ea + i);
        x[i] = v.x; x[i + 1] = v.y; x[i + 2] = v.z; x[i + 3] = v.w;
    }
    int pos = edge_pos[e];
    #pragma unroll
    for (int l = 0; l < 3; ++l) {
        float al[4];
        #pragma unroll
        for (int hh = 0; hh < 4; ++hh) {
            float acc = 0.f;
            #pragma unroll
            for (int i = 0; i < 16; ++i) acc += x[i] * wsh[l * 64 + hh * 16 + i];
            al[hh] = acc;
        }
        ae_csr[(size_t)l * N_EDGES + pos] = make_float4(al[0], al[1], al[2], al[3]);
    }
}

// ---------------------------------------------------------------- MFMA GEMM (verified; unchanged)
template <int NKT>
__global__ __launch_bounds__(256) void gemm16_kernel(const __half* __restrict__ A16,
                                                     const __half* __restrict__ Wt16,
                                                     __half* __restrict__ C16, int M,
                                                     const float* __restrict__ att_src,
                                                     const float* __restrict__ att_dst,
                                                     float* __restrict__ a_src,
                                                     float* __restrict__ a_dst) {
    constexpr int K = NKT * 32;
    __shared__ __align__(16) _Float16 lds[64 * 264];
    int t = threadIdx.x;
    int w = t >> 6, l = t & 63;
    int cg = l & 15, gg = l >> 4;
    int m0 = blockIdx.x * 64;

    {
        int row = (t >> 6) * 16 + (t & 15);
        int k8 = (t >> 4) & 3;
        int rg = m0 + row;
        if (rg >= M) rg = M - 1;
        const _Float16* ag = (const _Float16*)A16 + (size_t)rg * K + k8 * 8;
        f16x8 tmp[NKT];
        #pragma unroll
        for (int j = 0; j < NKT; ++j) tmp[j] = *(const f16x8*)(ag + j * 32);
        #pragma unroll
        for (int j = 0; j < NKT; ++j) *(f16x8*)&lds[(size_t)(j * 256 + t) * 8] = tmp[j];
    }
    __syncthreads();

    f32x4 acc[4][4] = {};
    const _Float16* bg = (const _Float16*)Wt16 + (size_t)(w * 64 + cg) * K + gg * 8;
    #pragma unroll 2
    for (int kt = 0; kt < NKT; ++kt) {
        f16x8 bf[4], af[4];
        #pragma unroll
        for (int ni = 0; ni < 4; ++ni)
            bf[ni] = *(const f16x8*)(bg + (size_t)(ni * 16) * K + kt * 32);
        #pragma unroll
        for (int mi = 0; mi < 4; ++mi)
            af[mi] = *(const f16x8*)&lds[(size_t)(kt * 256 + mi * 64 + l) * 8];
        #pragma unroll
        for (int mi = 0; mi < 4; ++mi)
            #pragma unroll
            for (int ni = 0; ni < 4; ++ni)
                acc[mi][ni] = __builtin_amdgcn_mfma_f32_16x16x32_f16(af[mi], bf[ni], acc[mi][ni], 0, 0, 0);
    }

    {
        float avs[4], avd[4];
        #pragma unroll
        for (int ni = 0; ni < 4; ++ni) {
            avs[ni] = att_src[w * 64 + ni * 16 + cg];
            avd[ni] = att_dst[w * 64 + ni * 16 + cg];
        }
        #pragma unroll
        for (int mi = 0; mi < 4; ++mi)
            #pragma unroll
            for (int reg = 0; reg < 4; ++reg) {
                float ps = acc[mi][0][reg] * avs[0] + acc[mi][1][reg] * avs[1]
                         + acc[mi][2][reg] * avs[2] + acc[mi][3][reg] * avs[3];
                float pd = acc[mi][0][reg] * avd[0] + acc[mi][1][reg] * avd[1]
                         + acc[mi][2][reg] * avd[2] + acc[mi][3][reg] * avd[3];
                #pragma unroll
                for (int o = 1; o < 16; o <<= 1) {
                    ps += __shfl_xor(ps, o, 64);
                    pd += __shfl_xor(pd, o, 64);
                }
                int m = m0 + mi * 16 + gg * 4 + reg;
                if (cg == 0 && m < M) {
                    a_src[(size_t)m * 4 + w] = ps;
                    a_dst[(size_t)m * 4 + w] = pd;
                }
            }
    }

    __syncthreads();
    #pragma unroll
    for (int mi = 0; mi < 4; ++mi)
        #pragma unroll
        for (int ni = 0; ni < 4; ++ni)
            #pragma unroll
            for (int reg = 0; reg < 4; ++reg) {
                int row = mi * 16 + gg * 4 + reg;
                int col = w * 64 + ni * 16 + cg;
                lds[row * 264 + col] = (_Float16)acc[mi][ni][reg];
            }
    __syncthreads();
    #pragma unroll
    for (int i = 0; i < 8; ++i) {
        int g = i * 256 + t;
        int row = g >> 5, cw = g & 31;
        int m = m0 + row;
        if (m < M) {
            f16x8 v = *(const f16x8*)&lds[row * 264 + cw * 8];
            *(f16x8*)((_Float16*)C16 + (size_t)m * HC + cw * 8) = v;
        }
    }
}

// ---------------------------------------------------------------- aggregate3: precomputed-weight softmax + b128 gather
// wave per node. Pass A: logits -> max -> exp weights cached in LDS + denoms (butterfly reduces).
// Pass B: group g (32 lanes) handles edge 2*it+g; lane j loads h16[s][8j..8j+7] (b128, 512B/group);
// cross-group shfl reduce at the end. No __syncthreads (wave-private LDS).
__global__ __launch_bounds__(256) void aggregate3_kernel(const int* __restrict__ src_csr,
                                                         const float4* __restrict__ ae_csr,
                                                         const int* __restrict__ row_start,
                                                         const int* __restrict__ counts,
                                                         const float* __restrict__ a_src,
                                                         const float* __restrict__ a_dst,
                                                         const __half* __restrict__ h16,
                                                         const float* __restrict__ bias,
                                                         __half* __restrict__ out16) {
    __shared__ float wlds[4][4][CAP + 1];   // [wave][head][edge], padded
    int wid = threadIdx.x >> 6, lane = threadIdx.x & 63;
    int n = blockIdx.x * 4 + wid;           // grid = 5000 exactly
    int start = row_start[n];
    int deg = counts[n];
    const float4* ae = ae_csr + start;
    const int* sp = src_csr + start;
    float4 ad = *(const float4*)(a_dst + (size_t)n * 4);

    // ---- pass A1: logits + per-head max
    float m0 = -INFINITY, m1 = -INFINITY, m2 = -INFINITY, m3 = -INFINITY;
    for (int i = lane; i < deg; i += 64) {
        float4 a = ae[i];
        int s = sp[i];
        float4 as = *(const float4*)(a_src + (size_t)s * 4);
        float v0 = a.x + as.x + ad.x; v0 = v0 > 0.f ? v0 : NEG_SLOPE * v0;
        float v1 = a.y + as.y + ad.y; v1 = v1 > 0.f ? v1 : NEG_SLOPE * v1;
        float v2 = a.z + as.z + ad.z; v2 = v2 > 0.f ? v2 : NEG_SLOPE * v2;
        float v3 = a.w + as.w + ad.w; v3 = v3 > 0.f ? v3 : NEG_SLOPE * v3;
        if (i < CAP) {
            wlds[wid][0][i] = v0; wlds[wid][1][i] = v1;
            wlds[wid][2][i] = v2; wlds[wid][3][i] = v3;
        }
        m0 = fmaxf(m0, v0); m1 = fmaxf(m1, v1);
        m2 = fmaxf(m2, v2); m3 = fmaxf(m3, v3);
    }
    #pragma unroll
    for (int o = 32; o > 0; o >>= 1) {
        m0 = fmaxf(m0, __shfl_xor(m0, o, 64));
        m1 = fmaxf(m1, __shfl_xor(m1, o, 64));
        m2 = fmaxf(m2, __shfl_xor(m2, o, 64));
        m3 = fmaxf(m3, __shfl_xor(m3, o, 64));
    }

    // ---- pass A2: exp weights (cached) + per-head denom
    float d0 = 0.f, d1 = 0.f, d2 = 0.f, d3 = 0.f;
    for (int i = lane; i < deg; i += 64) {
        float v0, v1, v2, v3;
        if (i < CAP) {
            v0 = wlds[wid][0][i]; v1 = wlds[wid][1][i];
            v2 = wlds[wid][2][i]; v3 = wlds[wid][3][i];
        } else {
            float4 a = ae[i];
            int s = sp[i];
            float4 as = *(const float4*)(a_src + (size_t)s * 4);
            v0 = a.x + as.x + ad.x; v0 = v0 > 0.f ? v0 : NEG_SLOPE * v0;
            v1 = a.y + as.y + ad.y; v1 = v1 > 0.f ? v1 : NEG_SLOPE * v1;
            v2 = a.z + as.z + ad.z; v2 = v2 > 0.f ? v2 : NEG_SLOPE * v2;
            v3 = a.w + as.w + ad.w; v3 = v3 > 0.f ? v3 : NEG_SLOPE * v3;
        }
        float e0 = __expf(v0 - m0);
        float e1 = __expf(v1 - m1);
        float e2 = __expf(v2 - m2);
        float e3 = __expf(v3 - m3);
        d0 += e0; d1 += e1; d2 += e2; d3 += e3;
        if (i < CAP) {
            wlds[wid][0][i] = e0; wlds[wid][1][i] = e1;
            wlds[wid][2][i] = e2; wlds[wid][3][i] = e3;
        }
    }
    #pragma unroll
    for (int o = 32; o > 0; o >>= 1) {
        d0 += __shfl_xor(d0, o, 64);
        d1 += __shfl_xor(d1, o, 64);
        d2 += __shfl_xor(d2, o, 64);
        d3 += __shfl_xor(d3, o, 64);
    }

    // ---- pass B: 2 edges/iter, lane j of group g loads 8 chans (b128)
    int g = lane >> 5, j = lane & 31;
    int head = j >> 3;
    float mh = (head < 2) ? (head == 0 ? m0 : m1) : (head == 2 ? m2 : m3);
    float dh = (head < 2) ? (head == 0 ? d0 : d1) : (head == 2 ? d2 : d3);
    float adh = (head < 2) ? (head == 0 ? ad.x : ad.y) : (head == 2 ? ad.z : ad.w);

    float acc[8] = {};
    int niter = (deg + 1) >> 1;
    #pragma unroll 2
    for (int it = 0; it < niter; ++it) {
        int e = it * 2 + g;
        bool valid = e < deg;
        int ec = valid ? e : deg - 1;
        int s = sp[ec];
        float wgt;
        if (ec < CAP) {
            wgt = wlds[wid][head][ec];
        } else {
            float4 a = ae[ec];
            float aa = (head < 2) ? (head == 0 ? a.x : a.y) : (head == 2 ? a.z : a.w);
            const float* asp = a_src + (size_t)s * 4;
            float v = aa + asp[head] + adh;
            v = v > 0.f ? v : NEG_SLOPE * v;
            wgt = __expf(v - mh);
        }
        if (!valid) wgt = 0.f;
        f16x8 hv = *(const f16x8*)((const _Float16*)h16 + (size_t)s * HC + j * 8);
        #pragma unroll
        for (int q = 0; q < 8; ++q) acc[q] += wgt * (float)hv[q];
    }
    // cross-group reduce (groups covered disjoint edges, same channels)
    #pragma unroll
    for (int q = 0; q < 8; ++q) acc[q] += __shfl_xor(acc[q], 32, 64);

    if (g == 0) {
        float invd = 1.f / (dh + EPSF);
        float4 b0 = *(const float4*)(bias + j * 8);
        float4 b1 = *(const float4*)(bias + j * 8 + 4);
        float r[8];
        r[0] = fmaxf(acc[0] * invd + b0.x, 0.f);
        r[1] = fmaxf(acc[1] * invd + b0.y, 0.f);
        r[2] = fmaxf(acc[2] * invd + b0.z, 0.f);
        r[3] = fmaxf(acc[3] * invd + b0.w, 0.f);
        r[4] = fmaxf(acc[4] * invd + b1.x, 0.f);
        r[5] = fmaxf(acc[5] * invd + b1.y, 0.f);
        r[6] = fmaxf(acc[6] * invd + b1.z, 0.f);
        r[7] = fmaxf(acc[7] * invd + b1.w, 0.f);
        f16x8 o;
        #pragma unroll
        for (int q = 0; q < 8; ++q) o[q] = (_Float16)r[q];
        *(f16x8*)((_Float16*)out16 + (size_t)n * HC + j * 8) = o;
    }
}

// ---------------------------------------------------------------- pooling (batch is sorted), fp16 input
#define NPB 100
__global__ __launch_bounds__(256) void pool_kernel(const __half* __restrict__ h,
                                                   const int* __restrict__ batch,
                                                   float* __restrict__ pooled,
                                                   int* __restrict__ gcounts) {
    int t = threadIdx.x;
    int n0 = blockIdx.x * NPB;
    int n1 = n0 + NPB;
    if (n1 > N_NODES) n1 = N_NODES;
    if (n0 >= N_NODES) return;
    int cur = batch[n0];
    float acc = 0.f;
    int cnt = 0;
    for (int n = n0; n < n1; ++n) {
        int g = batch[n];
        if (g != cur) {
            atomicAdd(&pooled[cur * HC + t], acc);
            if (t == 0) atomicAdd(&gcounts[cur], cnt);
            acc = 0.f; cnt = 0; cur = g;
        }
        acc += __half2float(h[(size_t)n * HC + t]);
        cnt++;
    }
    atomicAdd(&pooled[cur * HC + t], acc);
    if (t == 0) atomicAdd(&gcounts[cur], cnt);
}

__global__ __launch_bounds__(256) void finalize_kernel(const float* __restrict__ pooled,
                                                       const int* __restrict__ gcounts,
                                                       float* __restrict__ out) {
    int g = blockIdx.x, t = threadIdx.x;
    float c = (float)(gcounts[g] > 1 ? gcounts[g] : 1);
    out[g * HC + t] = tanhf(pooled[g * HC + t] / c);
}

// ---------------------------------------------------------------- launch
extern "C" void kernel_launch(void* const* d_in, const int* in_sizes, int n_in,
                              void* d_out, int out_size, void* d_ws, size_t ws_size,
                              hipStream_t stream) {
    const float* x         = (const float*)d_in[0];
    const int*   ei        = (const int*)d_in[1];
    const float* edge_attr = (const float*)d_in[2];
    const int*   batch     = (const int*)d_in[3];
    const float* Wl[3]  = {(const float*)d_in[4],  (const float*)d_in[10], (const float*)d_in[16]};
    const float* Wel[3] = {(const float*)d_in[5],  (const float*)d_in[11], (const float*)d_in[17]};
    const float* asl[3] = {(const float*)d_in[6],  (const float*)d_in[12], (const float*)d_in[18]};
    const float* adl[3] = {(const float*)d_in[7],  (const float*)d_in[13], (const float*)d_in[19]};
    const float* ael[3] = {(const float*)d_in[8],  (const float*)d_in[14], (const float*)d_in[20]};
    const float* bl[3]  = {(const float*)d_in[9],  (const float*)d_in[15], (const float*)d_in[21]};
    float* out = (float*)d_out;

    // workspace carve (256B aligned)
    char* p = (char*)d_ws;
    auto alloc = [&](size_t bytes) -> void* {
        void* r = (void*)p;
        p += (bytes + 255) & ~(size_t)255;
        return r;
    };
    __half* x16       = (__half*)alloc((size_t)N_NODES * OBS * 2);
    __half* hA16      = (__half*)alloc((size_t)N_NODES * HC * 2);
    __half* hB16      = (__half*)alloc((size_t)N_NODES * HC * 2);
    __half* wt0       = (__half*)alloc((size_t)HC * OBS * 2);
    __half* wt1       = (__half*)alloc((size_t)HC * HC * 2);
    __half* wt2       = (__half*)alloc((size_t)HC * HC * 2);
    float* a_src      = (float*)alloc((size_t)N_NODES * 4 * 4);
    float* a_dst      = (float*)alloc((size_t)N_NODES * 4 * 4);
    float4* ae_csr    = (float4*)alloc((size_t)3 * N_EDGES * 16);
    int* counts       = (int*)alloc((size_t)N_NODES * 4);
    int* row_start    = (int*)alloc((size_t)N_NODES * 4);
    int* cursor       = (int*)alloc((size_t)N_NODES * 4);
    int* src_csr      = (int*)alloc((size_t)N_EDGES * 4);
    int* edge_pos     = (int*)alloc((size_t)N_EDGES * 4);
    float* w_eff3     = (float*)alloc(192 * 4);
    float* pooled     = (float*)alloc((size_t)N_GRAPHS * HC * 4);
    int* gcounts      = (int*)alloc((size_t)N_GRAPHS * 4);
    int* blk_tot      = (int*)alloc((size_t)N_SCAN_BLOCKS * 4);

    // fused zero + conversions + weff (no inter-deps)
    zero3_kernel<<<N_SCAN_BLOCKS, 256, 0, stream>>>(counts, pooled, gcounts);
    cvtwt_kernel<<<CVT_BLOCKS + OBS + HC + HC, 256, 0, stream>>>(x, x16, Wl[0], Wl[1], Wl[2],
                                                                 wt0, wt1, wt2);
    weff3_kernel<<<3, 64, 0, stream>>>(Wel[0], ael[0], Wel[1], ael[1], Wel[2], ael[2], w_eff3);

    // CSR build over dst
    count_kernel<<<N_EDGES / 256, 256, 0, stream>>>(ei, counts);
    scan_local_kernel<<<N_SCAN_BLOCKS, 256, 0, stream>>>(counts, row_start, blk_tot);
    scan_add_kernel<<<N_SCAN_BLOCKS, 256, 0, stream>>>(row_start, blk_tot, cursor);
    fill_kernel<<<N_EDGES / 256, 256, 0, stream>>>(ei, cursor, src_csr, edge_pos);

    // all-layer edge dots in CSR order
    ae3_kernel<<<N_EDGES / 256, 256, 0, stream>>>(edge_attr, edge_pos, w_eff3, ae_csr);

    const int ngrid = (N_NODES + 63) / 64;
    const __half* wtl[3] = {wt0, wt1, wt2};
    const __half* cur_in = x16;
    for (int l = 0; l < 3; ++l) {
        if (l == 0)
            gemm16_kernel<2><<<ngrid, 256, 0, stream>>>(cur_in, wtl[l], hA16, N_NODES,
                                                        asl[l], adl[l], a_src, a_dst);
        else
            gemm16_kernel<8><<<ngrid, 256, 0, stream>>>(cur_in, wtl[l], hA16, N_NODES,
                                                        asl[l], adl[l], a_src, a_dst);
        aggregate3_kernel<<<N_NODES / 4, 256, 0, stream>>>(src_csr, ae_csr + (size_t)l * N_EDGES,
                                                           row_start, counts, a_src, a_dst,
                                                           hA16, bl[l], hB16);
        cur_in = hB16;
    }

    // global mean pool + tanh
    pool_kernel<<<(N_NODES + NPB - 1) / NPB, 256, 0, stream>>>(hB16, batch, pooled, gcounts);
    finalize_kernel<<<N_GRAPHS, 256, 0, stream>>>(pooled, gcounts, out);
}

// Round 10
// 226.521 us; speedup vs baseline: 1.3697x; 1.0794x over previous
//
#include <hip/hip_runtime.h>
#include <hip/hip_bf16.h>
#include <hip/hip_fp16.h>
#include <math.h>

#define N_NODES 20000
#define N_EDGES 320000
#define N_GRAPHS 64
#define OBS 64
#define EDGE_DIM 16
#define HEADS 4
#define HID 64
#define HC 256            // HEADS*HID
#define NEG_SLOPE 0.2f
#define EPSF 1e-16f
#define N_SCAN_BLOCKS ((N_NODES + 255) / 256)   // 79
#define CVT_BLOCKS (N_NODES * OBS / 4 / 256)    // 1250
#define CAP 64            // per-node LDS weight cache (edges)

typedef _Float16 f16x8 __attribute__((ext_vector_type(8)));
typedef float f32x4 __attribute__((ext_vector_type(4)));

// ---------------------------------------------------------------- fused setup: zeros + x->f16 + 3x Wt + w_eff3
// blocks [0,79): zero; [79, 79+1250): cvt; then wt0(64), wt1(256), wt2(256), weff3(3)
#define SB_ZERO  N_SCAN_BLOCKS
#define SB_CVT   (SB_ZERO + CVT_BLOCKS)
#define SB_WT0   (SB_CVT + OBS)
#define SB_WT1   (SB_WT0 + HC)
#define SB_WT2   (SB_WT1 + HC)
#define SB_TOT   (SB_WT2 + 3)
__global__ __launch_bounds__(256) void setup_kernel(int* __restrict__ counts,
                                                    float* __restrict__ pooled,
                                                    int* __restrict__ gcounts,
                                                    const float* __restrict__ x, __half* __restrict__ x16,
                                                    const float* __restrict__ W0, const float* __restrict__ W1,
                                                    const float* __restrict__ W2,
                                                    __half* __restrict__ wt0, __half* __restrict__ wt1,
                                                    __half* __restrict__ wt2,
                                                    const float* __restrict__ We0, const float* __restrict__ ae0,
                                                    const float* __restrict__ We1, const float* __restrict__ ae1,
                                                    const float* __restrict__ We2, const float* __restrict__ ae2,
                                                    float* __restrict__ w_eff3) {
    int b = blockIdx.x, t = threadIdx.x;
    if (b < SB_ZERO) {
        int i = b * 256 + t;
        if (i < N_NODES) counts[i] = 0;
        if (i < N_GRAPHS * HC) pooled[i] = 0.f;
        if (i < N_GRAPHS) gcounts[i] = 0;
    } else if (b < SB_CVT) {
        int i = ((b - SB_ZERO) * 256 + t) * 4;
        float4 v = *(const float4*)(x + i);
        *(__half2*)(x16 + i)     = __floats2half2_rn(v.x, v.y);
        *(__half2*)(x16 + i + 2) = __floats2half2_rn(v.z, v.w);
    } else if (b < SB_WT0) {
        int k = b - SB_CVT;
        wt0[(size_t)t * OBS + k] = __float2half(W0[(size_t)k * HC + t]);
    } else if (b < SB_WT1) {
        int k = b - SB_WT0;
        wt1[(size_t)t * HC + k] = __float2half(W1[(size_t)k * HC + t]);
    } else if (b < SB_WT2) {
        int k = b - SB_WT1;
        wt2[(size_t)t * HC + k] = __float2half(W2[(size_t)k * HC + t]);
    } else {
        int l = b - SB_WT2;
        if (t >= 64) return;
        const float* We = (l == 0) ? We0 : (l == 1) ? We1 : We2;
        const float* ae = (l == 0) ? ae0 : (l == 1) ? ae1 : ae2;
        int hh = t >> 4, d = t & 15;
        float acc = 0.f;
        #pragma unroll 8
        for (int c = 0; c < HID; ++c)
            acc += We[d * HC + hh * HID + c] * ae[hh * HID + c];
        w_eff3[l * 64 + hh * 16 + d] = acc;
    }
}

// ---------------------------------------------------------------- CSR build
__global__ __launch_bounds__(256) void count_kernel(const int* __restrict__ ei, int* __restrict__ counts) {
    int e = blockIdx.x * 256 + threadIdx.x;
    if (e >= N_EDGES) return;
    atomicAdd(&counts[ei[N_EDGES + e]], 1);
}

__global__ __launch_bounds__(256) void scan_local_kernel(const int* __restrict__ counts,
                                                         int* __restrict__ row_start,
                                                         int* __restrict__ blk_tot) {
    int b = blockIdx.x, t = threadIdx.x;
    int i = b * 256 + t;
    int v = (i < N_NODES) ? counts[i] : 0;
    int lane = t & 63, w = t >> 6;
    int x = v;
    #pragma unroll
    for (int off = 1; off < 64; off <<= 1) {
        int y = __shfl_up(x, off, 64);
        if (lane >= off) x += y;
    }
    __shared__ int wsum[4];
    __shared__ int woff[4];
    if (lane == 63) wsum[w] = x;
    __syncthreads();
    if (t == 0) {
        int s = 0;
        #pragma unroll
        for (int k = 0; k < 4; ++k) { woff[k] = s; s += wsum[k]; }
        blk_tot[b] = s;
    }
    __syncthreads();
    if (i < N_NODES) row_start[i] = x - v + woff[w];
}

__global__ __launch_bounds__(256) void scan_add_kernel(int* __restrict__ row_start,
                                                       const int* __restrict__ blk_tot,
                                                       int* __restrict__ cursor) {
    __shared__ int sd[128];
    int b = blockIdx.x, t = threadIdx.x;
    if (t < 128) sd[t] = (t < b && t < N_SCAN_BLOCKS) ? blk_tot[t] : 0;
    __syncthreads();
    #pragma unroll
    for (int off = 64; off >= 1; off >>= 1) {
        if (t < off) sd[t] += sd[t + off];
        __syncthreads();
    }
    int base = sd[0];
    int i = b * 256 + t;
    if (i < N_NODES) {
        int r = row_start[i] + base;
        row_start[i] = r;
        cursor[i] = r;
    }
}

// ---------------------------------------------------------------- fill + per-edge dots (all layers) -> CSR order
__global__ __launch_bounds__(256) void fill_ae_kernel(const int* __restrict__ ei,
                                                      const float* __restrict__ edge_attr,
                                                      const float* __restrict__ w_eff3,
                                                      int* __restrict__ cursor,
                                                      int* __restrict__ src_csr,
                                                      float4* __restrict__ ae_csr) {
    __shared__ float wsh[192];
    int t = threadIdx.x;
    if (t < 192) wsh[t] = w_eff3[t];
    __syncthreads();
    int e = blockIdx.x * 256 + t;
    if (e >= N_EDGES) return;
    int s = ei[e];
    int d = ei[N_EDGES + e];
    int pos = atomicAdd(&cursor[d], 1);
    src_csr[pos] = s;
    const float* ea = edge_attr + (size_t)e * EDGE_DIM;
    float x[16];
    #pragma unroll
    for (int i = 0; i < 16; i += 4) {
        float4 v = *(const float4*)(ea + i);
        x[i] = v.x; x[i + 1] = v.y; x[i + 2] = v.z; x[i + 3] = v.w;
    }
    #pragma unroll
    for (int l = 0; l < 3; ++l) {
        float al[4];
        #pragma unroll
        for (int hh = 0; hh < 4; ++hh) {
            float acc = 0.f;
            #pragma unroll
            for (int i = 0; i < 16; ++i) acc += x[i] * wsh[l * 64 + hh * 16 + i];
            al[hh] = acc;
        }
        ae_csr[(size_t)l * N_EDGES + pos] = make_float4(al[0], al[1], al[2], al[3]);
    }
}

// ---------------------------------------------------------------- MFMA GEMM (verified; unchanged)
template <int NKT>
__global__ __launch_bounds__(256) void gemm16_kernel(const __half* __restrict__ A16,
                                                     const __half* __restrict__ Wt16,
                                                     __half* __restrict__ C16, int M,
                                                     const float* __restrict__ att_src,
                                                     const float* __restrict__ att_dst,
                                                     float* __restrict__ a_src,
                                                     float* __restrict__ a_dst) {
    constexpr int K = NKT * 32;
    __shared__ __align__(16) _Float16 lds[64 * 264];
    int t = threadIdx.x;
    int w = t >> 6, l = t & 63;
    int cg = l & 15, gg = l >> 4;
    int m0 = blockIdx.x * 64;

    {
        int row = (t >> 6) * 16 + (t & 15);
        int k8 = (t >> 4) & 3;
        int rg = m0 + row;
        if (rg >= M) rg = M - 1;
        const _Float16* ag = (const _Float16*)A16 + (size_t)rg * K + k8 * 8;
        f16x8 tmp[NKT];
        #pragma unroll
        for (int j = 0; j < NKT; ++j) tmp[j] = *(const f16x8*)(ag + j * 32);
        #pragma unroll
        for (int j = 0; j < NKT; ++j) *(f16x8*)&lds[(size_t)(j * 256 + t) * 8] = tmp[j];
    }
    __syncthreads();

    f32x4 acc[4][4] = {};
    const _Float16* bg = (const _Float16*)Wt16 + (size_t)(w * 64 + cg) * K + gg * 8;
    #pragma unroll 2
    for (int kt = 0; kt < NKT; ++kt) {
        f16x8 bf[4], af[4];
        #pragma unroll
        for (int ni = 0; ni < 4; ++ni)
            bf[ni] = *(const f16x8*)(bg + (size_t)(ni * 16) * K + kt * 32);
        #pragma unroll
        for (int mi = 0; mi < 4; ++mi)
            af[mi] = *(const f16x8*)&lds[(size_t)(kt * 256 + mi * 64 + l) * 8];
        #pragma unroll
        for (int mi = 0; mi < 4; ++mi)
            #pragma unroll
            for (int ni = 0; ni < 4; ++ni)
                acc[mi][ni] = __builtin_amdgcn_mfma_f32_16x16x32_f16(af[mi], bf[ni], acc[mi][ni], 0, 0, 0);
    }

    {
        float avs[4], avd[4];
        #pragma unroll
        for (int ni = 0; ni < 4; ++ni) {
            avs[ni] = att_src[w * 64 + ni * 16 + cg];
            avd[ni] = att_dst[w * 64 + ni * 16 + cg];
        }
        #pragma unroll
        for (int mi = 0; mi < 4; ++mi)
            #pragma unroll
            for (int reg = 0; reg < 4; ++reg) {
                float ps = acc[mi][0][reg] * avs[0] + acc[mi][1][reg] * avs[1]
                         + acc[mi][2][reg] * avs[2] + acc[mi][3][reg] * avs[3];
                float pd = acc[mi][0][reg] * avd[0] + acc[mi][1][reg] * avd[1]
                         + acc[mi][2][reg] * avd[2] + acc[mi][3][reg] * avd[3];
                #pragma unroll
                for (int o = 1; o < 16; o <<= 1) {
                    ps += __shfl_xor(ps, o, 64);
                    pd += __shfl_xor(pd, o, 64);
                }
                int m = m0 + mi * 16 + gg * 4 + reg;
                if (cg == 0 && m < M) {
                    a_src[(size_t)m * 4 + w] = ps;
                    a_dst[(size_t)m * 4 + w] = pd;
                }
            }
    }

    __syncthreads();
    #pragma unroll
    for (int mi = 0; mi < 4; ++mi)
        #pragma unroll
        for (int ni = 0; ni < 4; ++ni)
            #pragma unroll
            for (int reg = 0; reg < 4; ++reg) {
                int row = mi * 16 + gg * 4 + reg;
                int col = w * 64 + ni * 16 + cg;
                lds[row * 264 + col] = (_Float16)acc[mi][ni][reg];
            }
    __syncthreads();
    #pragma unroll
    for (int i = 0; i < 8; ++i) {
        int g = i * 256 + t;
        int row = g >> 5, cw = g & 31;
        int m = m0 + row;
        if (m < M) {
            f16x8 v = *(const f16x8*)&lds[row * 264 + cw * 8];
            *(f16x8*)((_Float16*)C16 + (size_t)m * HC + cw * 8) = v;
        }
    }
}

// ---------------------------------------------------------------- aggregate4: softmax + 4-deep pipelined b128 gather
// wave per node. Pass A: logits -> max -> exp weights in LDS + denoms.
// Pass B fast path (deg<=CAP, wave-uniform): batch 4 edges' (s,w), issue 4 b128 loads, then FMA.
__global__ __launch_bounds__(256) void aggregate4_kernel(const int* __restrict__ src_csr,
                                                         const float4* __restrict__ ae_csr,
                                                         const int* __restrict__ row_start,
                                                         const int* __restrict__ counts,
                                                         const float* __restrict__ a_src,
                                                         const float* __restrict__ a_dst,
                                                         const __half* __restrict__ h16,
                                                         const float* __restrict__ bias,
                                                         __half* __restrict__ out16) {
    __shared__ float wlds[4][4][CAP + 1];   // [wave][head][edge], padded
    int wid = threadIdx.x >> 6, lane = threadIdx.x & 63;
    int n = blockIdx.x * 4 + wid;           // grid = 5000 exactly
    int start = row_start[n];
    int deg = counts[n];
    const float4* ae = ae_csr + start;
    const int* sp = src_csr + start;
    float4 ad = *(const float4*)(a_dst + (size_t)n * 4);

    // ---- pass A1: logits + per-head max
    float m0 = -INFINITY, m1 = -INFINITY, m2 = -INFINITY, m3 = -INFINITY;
    for (int i = lane; i < deg; i += 64) {
        float4 a = ae[i];
        int s = sp[i];
        float4 as = *(const float4*)(a_src + (size_t)s * 4);
        float v0 = a.x + as.x + ad.x; v0 = v0 > 0.f ? v0 : NEG_SLOPE * v0;
        float v1 = a.y + as.y + ad.y; v1 = v1 > 0.f ? v1 : NEG_SLOPE * v1;
        float v2 = a.z + as.z + ad.z; v2 = v2 > 0.f ? v2 : NEG_SLOPE * v2;
        float v3 = a.w + as.w + ad.w; v3 = v3 > 0.f ? v3 : NEG_SLOPE * v3;
        if (i < CAP) {
            wlds[wid][0][i] = v0; wlds[wid][1][i] = v1;
            wlds[wid][2][i] = v2; wlds[wid][3][i] = v3;
        }
        m0 = fmaxf(m0, v0); m1 = fmaxf(m1, v1);
        m2 = fmaxf(m2, v2); m3 = fmaxf(m3, v3);
    }
    #pragma unroll
    for (int o = 32; o > 0; o >>= 1) {
        m0 = fmaxf(m0, __shfl_xor(m0, o, 64));
        m1 = fmaxf(m1, __shfl_xor(m1, o, 64));
        m2 = fmaxf(m2, __shfl_xor(m2, o, 64));
        m3 = fmaxf(m3, __shfl_xor(m3, o, 64));
    }

    // ---- pass A2: exp weights (cached) + per-head denom
    float d0 = 0.f, d1 = 0.f, d2 = 0.f, d3 = 0.f;
    for (int i = lane; i < deg; i += 64) {
        float v0, v1, v2, v3;
        if (i < CAP) {
            v0 = wlds[wid][0][i]; v1 = wlds[wid][1][i];
            v2 = wlds[wid][2][i]; v3 = wlds[wid][3][i];
        } else {
            float4 a = ae[i];
            int s = sp[i];
            float4 as = *(const float4*)(a_src + (size_t)s * 4);
            v0 = a.x + as.x + ad.x; v0 = v0 > 0.f ? v0 : NEG_SLOPE * v0;
            v1 = a.y + as.y + ad.y; v1 = v1 > 0.f ? v1 : NEG_SLOPE * v1;
            v2 = a.z + as.z + ad.z; v2 = v2 > 0.f ? v2 : NEG_SLOPE * v2;
            v3 = a.w + as.w + ad.w; v3 = v3 > 0.f ? v3 : NEG_SLOPE * v3;
        }
        float e0 = __expf(v0 - m0);
        float e1 = __expf(v1 - m1);
        float e2 = __expf(v2 - m2);
        float e3 = __expf(v3 - m3);
        d0 += e0; d1 += e1; d2 += e2; d3 += e3;
        if (i < CAP) {
            wlds[wid][0][i] = e0; wlds[wid][1][i] = e1;
            wlds[wid][2][i] = e2; wlds[wid][3][i] = e3;
        }
    }
    #pragma unroll
    for (int o = 32; o > 0; o >>= 1) {
        d0 += __shfl_xor(d0, o, 64);
        d1 += __shfl_xor(d1, o, 64);
        d2 += __shfl_xor(d2, o, 64);
        d3 += __shfl_xor(d3, o, 64);
    }

    // ---- pass B: group g handles edge 2*it+g; lane j loads 8 chans (b128)
    int g = lane >> 5, j = lane & 31;
    int head = j >> 3;
    float mh = (head < 2) ? (head == 0 ? m0 : m1) : (head == 2 ? m2 : m3);
    float dh = (head < 2) ? (head == 0 ? d0 : d1) : (head == 2 ? d2 : d3);
    float adh = (head < 2) ? (head == 0 ? ad.x : ad.y) : (head == 2 ? ad.z : ad.w);

    float acc[8] = {};
    int niter = (deg + 1) >> 1;
    if (deg <= CAP) {
        // fast path: weights all in LDS; 4-deep pipelined gather
        int it = 0;
        for (; it + 4 <= niter; it += 4) {
            int s_[4]; float w_[4]; f16x8 hv_[4];
            #pragma unroll
            for (int u = 0; u < 4; ++u) {
                int e = (it + u) * 2 + g;
                bool valid = e < deg;
                int ec = valid ? e : deg - 1;
                s_[u] = sp[ec];
                float wv = wlds[wid][head][ec];
                w_[u] = valid ? wv : 0.f;
            }
            #pragma unroll
            for (int u = 0; u < 4; ++u)
                hv_[u] = *(const f16x8*)((const _Float16*)h16 + (size_t)s_[u] * HC + j * 8);
            #pragma unroll
            for (int u = 0; u < 4; ++u)
                #pragma unroll
                for (int q = 0; q < 8; ++q) acc[q] += w_[u] * (float)hv_[u][q];
        }
        for (; it < niter; ++it) {
            int e = it * 2 + g;
            bool valid = e < deg;
            int ec = valid ? e : deg - 1;
            int s = sp[ec];
            float wv = wlds[wid][head][ec];
            float wgt = valid ? wv : 0.f;
            f16x8 hv = *(const f16x8*)((const _Float16*)h16 + (size_t)s * HC + j * 8);
            #pragma unroll
            for (int q = 0; q < 8; ++q) acc[q] += wgt * (float)hv[q];
        }
    } else {
        // slow path (deg > CAP): recompute weights beyond LDS cache
        for (int it = 0; it < niter; ++it) {
            int e = it * 2 + g;
            bool valid = e < deg;
            int ec = valid ? e : deg - 1;
            int s = sp[ec];
            float wgt;
            if (ec < CAP) {
                wgt = wlds[wid][head][ec];
            } else {
                float4 a = ae[ec];
                float aa = (head < 2) ? (head == 0 ? a.x : a.y) : (head == 2 ? a.z : a.w);
                const float* asp = a_src + (size_t)s * 4;
                float v = aa + asp[head] + adh;
                v = v > 0.f ? v : NEG_SLOPE * v;
                wgt = __expf(v - mh);
            }
            if (!valid) wgt = 0.f;
            f16x8 hv = *(const f16x8*)((const _Float16*)h16 + (size_t)s * HC + j * 8);
            #pragma unroll
            for (int q = 0; q < 8; ++q) acc[q] += wgt * (float)hv[q];
        }
    }
    // cross-group reduce (groups covered disjoint edges, same channels)
    #pragma unroll
    for (int q = 0; q < 8; ++q) acc[q] += __shfl_xor(acc[q], 32, 64);

    if (g == 0) {
        float invd = 1.f / (dh + EPSF);
        float4 b0 = *(const float4*)(bias + j * 8);
        float4 b1 = *(const float4*)(bias + j * 8 + 4);
        float r[8];
        r[0] = fmaxf(acc[0] * invd + b0.x, 0.f);
        r[1] = fmaxf(acc[1] * invd + b0.y, 0.f);
        r[2] = fmaxf(acc[2] * invd + b0.z, 0.f);
        r[3] = fmaxf(acc[3] * invd + b0.w, 0.f);
        r[4] = fmaxf(acc[4] * invd + b1.x, 0.f);
        r[5] = fmaxf(acc[5] * invd + b1.y, 0.f);
        r[6] = fmaxf(acc[6] * invd + b1.z, 0.f);
        r[7] = fmaxf(acc[7] * invd + b1.w, 0.f);
        f16x8 o;
        #pragma unroll
        for (int q = 0; q < 8; ++q) o[q] = (_Float16)r[q];
        *(f16x8*)((_Float16*)out16 + (size_t)n * HC + j * 8) = o;
    }
}

// ---------------------------------------------------------------- pooling (batch is sorted), fp16 input
#define NPB 100
__global__ __launch_bounds__(256) void pool_kernel(const __half* __restrict__ h,
                                                   const int* __restrict__ batch,
                                                   float* __restrict__ pooled,
                                                   int* __restrict__ gcounts) {
    int t = threadIdx.x;
    int n0 = blockIdx.x * NPB;
    int n1 = n0 + NPB;
    if (n1 > N_NODES) n1 = N_NODES;
    if (n0 >= N_NODES) return;
    int cur = batch[n0];
    float acc = 0.f;
    int cnt = 0;
    for (int n = n0; n < n1; ++n) {
        int g = batch[n];
        if (g != cur) {
            atomicAdd(&pooled[cur * HC + t], acc);
            if (t == 0) atomicAdd(&gcounts[cur], cnt);
            acc = 0.f; cnt = 0; cur = g;
        }
        acc += __half2float(h[(size_t)n * HC + t]);
        cnt++;
    }
    atomicAdd(&pooled[cur * HC + t], acc);
    if (t == 0) atomicAdd(&gcounts[cur], cnt);
}

__global__ __launch_bounds__(256) void finalize_kernel(const float* __restrict__ pooled,
                                                       const int* __restrict__ gcounts,
                                                       float* __restrict__ out) {
    int g = blockIdx.x, t = threadIdx.x;
    float c = (float)(gcounts[g] > 1 ? gcounts[g] : 1);
    out[g * HC + t] = tanhf(pooled[g * HC + t] / c);
}

// ---------------------------------------------------------------- launch
extern "C" void kernel_launch(void* const* d_in, const int* in_sizes, int n_in,
                              void* d_out, int out_size, void* d_ws, size_t ws_size,
                              hipStream_t stream) {
    const float* x         = (const float*)d_in[0];
    const int*   ei        = (const int*)d_in[1];
    const float* edge_attr = (const float*)d_in[2];
    const int*   batch     = (const int*)d_in[3];
    const float* Wl[3]  = {(const float*)d_in[4],  (const float*)d_in[10], (const float*)d_in[16]};
    const float* Wel[3] = {(const float*)d_in[5],  (const float*)d_in[11], (const float*)d_in[17]};
    const float* asl[3] = {(const float*)d_in[6],  (const float*)d_in[12], (const float*)d_in[18]};
    const float* adl[3] = {(const float*)d_in[7],  (const float*)d_in[13], (const float*)d_in[19]};
    const float* ael[3] = {(const float*)d_in[8],  (const float*)d_in[14], (const float*)d_in[20]};
    const float* bl[3]  = {(const float*)d_in[9],  (const float*)d_in[15], (const float*)d_in[21]};
    float* out = (float*)d_out;

    // workspace carve (256B aligned)
    char* p = (char*)d_ws;
    auto alloc = [&](size_t bytes) -> void* {
        void* r = (void*)p;
        p += (bytes + 255) & ~(size_t)255;
        return r;
    };
    __half* x16       = (__half*)alloc((size_t)N_NODES * OBS * 2);
    __half* hA16      = (__half*)alloc((size_t)N_NODES * HC * 2);
    __half* hB16      = (__half*)alloc((size_t)N_NODES * HC * 2);
    __half* wt0       = (__half*)alloc((size_t)HC * OBS * 2);
    __half* wt1       = (__half*)alloc((size_t)HC * HC * 2);
    __half* wt2       = (__half*)alloc((size_t)HC * HC * 2);
    float* a_src      = (float*)alloc((size_t)N_NODES * 4 * 4);
    float* a_dst      = (float*)alloc((size_t)N_NODES * 4 * 4);
    float4* ae_csr    = (float4*)alloc((size_t)3 * N_EDGES * 16);
    int* counts       = (int*)alloc((size_t)N_NODES * 4);
    int* row_start    = (int*)alloc((size_t)N_NODES * 4);
    int* cursor       = (int*)alloc((size_t)N_NODES * 4);
    int* src_csr      = (int*)alloc((size_t)N_EDGES * 4);
    float* w_eff3     = (float*)alloc(192 * 4);
    float* pooled     = (float*)alloc((size_t)N_GRAPHS * HC * 4);
    int* gcounts      = (int*)alloc((size_t)N_GRAPHS * 4);
    int* blk_tot      = (int*)alloc((size_t)N_SCAN_BLOCKS * 4);

    // fused setup (zeros, x16, Wt x3, w_eff3)
    setup_kernel<<<SB_TOT, 256, 0, stream>>>(counts, pooled, gcounts, x, x16,
                                             Wl[0], Wl[1], Wl[2], wt0, wt1, wt2,
                                             Wel[0], ael[0], Wel[1], ael[1], Wel[2], ael[2],
                                             w_eff3);

    // CSR build over dst + fused per-edge dots
    count_kernel<<<N_EDGES / 256, 256, 0, stream>>>(ei, counts);
    scan_local_kernel<<<N_SCAN_BLOCKS, 256, 0, stream>>>(counts, row_start, blk_tot);
    scan_add_kernel<<<N_SCAN_BLOCKS, 256, 0, stream>>>(row_start, blk_tot, cursor);
    fill_ae_kernel<<<N_EDGES / 256, 256, 0, stream>>>(ei, edge_attr, w_eff3, cursor,
                                                      src_csr, ae_csr);

    const int ngrid = (N_NODES + 63) / 64;
    const __half* wtl[3] = {wt0, wt1, wt2};
    const __half* cur_in = x16;
    for (int l = 0; l < 3; ++l) {
        if (l == 0)
            gemm16_kernel<2><<<ngrid, 256, 0, stream>>>(cur_in, wtl[l], hA16, N_NODES,
                                                        asl[l], adl[l], a_src, a_dst);
        else
            gemm16_kernel<8><<<ngrid, 256, 0, stream>>>(cur_in, wtl[l], hA16, N_NODES,
                                                        asl[l], adl[l], a_src, a_dst);
        aggregate4_kernel<<<N_NODES / 4, 256, 0, stream>>>(src_csr, ae_csr + (size_t)l * N_EDGES,
                                                           row_start, counts, a_src, a_dst,
                                                           hA16, bl[l], hB16);
        cur_in = hB16;
    }

    // global mean pool + tanh
    pool_kernel<<<(N_NODES + NPB - 1) / NPB, 256, 0, stream>>>(hB16, batch, pooled, gcounts);
    finalize_kernel<<<N_GRAPHS, 256, 0, stream>>>(pooled, gcounts, out);
}